// Round 5
// baseline (355.098 us; speedup 1.0000x reference)
//
#include <hip/hip_runtime.h>

// MultiHeadAttention: BS=4, N=2048, D=512, H=8, DK=64. fp32 in/out, bf16 MFMA compute.
// Round 10: K via asm-pinned 4-deep register-rotated global loads with counted
// vmcnt waits (R4's JIT loads were compiler-sunk to use -> latency-bound; R3's
// full-tile prefetch spilled). lgkm-only barriers keep V/mask prefetch in flight.
// cvt4 merged into cvt3 (one kernel: QKV + weights + mask-pack slices).

#define BS_    4
#define NSEQ   2048
#define DMODEL 512
#define NH     8
#define DKH    64
#define MROWS  (BS_ * NSEQ)   // 8192
#define NW32   (NSEQ / 32)    // 64 mask words per row
#define NWORDS (BS_ * NSEQ * NSEQ / 32)  // 524288 packed mask words

typedef unsigned short ushort_t;
typedef __attribute__((ext_vector_type(8))) short short8;   // 8 bf16 (4 VGPRs)
typedef __attribute__((ext_vector_type(4))) float floatx4;  // 4 fp32 acc

__device__ __forceinline__ ushort_t f2bf(float f) {
    unsigned int x = __builtin_bit_cast(unsigned int, f);
    unsigned int lsb = (x >> 16) & 1u;
    x += 0x7fffu + lsb;          // round-to-nearest-even
    return (ushort_t)(x >> 16);
}
__device__ __forceinline__ floatx4 mfma_bf16(short8 a, short8 b, floatx4 c) {
    return __builtin_amdgcn_mfma_f32_16x16x32_bf16(a, b, c, 0, 0, 0);
}
__device__ __forceinline__ void gld16(const ushort_t* g, ushort_t* l) {
    __builtin_amdgcn_global_load_lds(
        (const __attribute__((address_space(1))) unsigned int*)g,
        (__attribute__((address_space(3))) unsigned int*)l, 16, 0, 0);
}
__device__ __forceinline__ unsigned int cvt_pk_bf16(float lo, float hi) {
    unsigned int r;
    asm("v_cvt_pk_bf16_f32 %0, %1, %2" : "=v"(r) : "v"(lo), "v"(hi));
    return r;
}
// barrier that waits only on LDS ops (no vmcnt drain -> global prefetch stays in flight)
__device__ __forceinline__ void lgkm_barrier() {
    asm volatile("s_waitcnt lgkmcnt(0)" ::: "memory");
    __builtin_amdgcn_s_barrier();
    __builtin_amdgcn_sched_barrier(0);
}

// asm-pinned 16B global load (cannot be sunk by the scheduler)
#define KLOAD(DST, PTR) \
    asm volatile("global_load_dwordx4 %0, %1, off" : "=v"(DST) : "v"(PTR))
// counted wait; ties the K regs so dependent MFMAs cannot hoist above it
#define KWAIT(N, A, B) do {                                      \
    asm volatile("s_waitcnt vmcnt(" #N ")" : "+v"(A), "+v"(B));  \
    __builtin_amdgcn_sched_barrier(0);                           \
} while (0)

// ---------------- fp32 -> bf16 converts + weights + att_mas bit-pack ----------------
// grid (4096, 5): y=0..2 QKV slices; y=3 weights (WQ,WK,WV,WO contiguous); y=4 mask
__global__ __launch_bounds__(256) void cvt_all(const float* __restrict__ a,
                                               const float* __restrict__ b,
                                               const float* __restrict__ c,
                                               const float* __restrict__ wq,
                                               const float* __restrict__ wk,
                                               const float* __restrict__ wv,
                                               const float* __restrict__ wo,
                                               const float* __restrict__ am,
                                               ushort_t* __restrict__ dst,
                                               ushort_t* __restrict__ wdst,
                                               unsigned int* __restrict__ mb, int n4) {
    const int i = blockIdx.x * blockDim.x + threadIdx.x;
    const int yy = blockIdx.y;
    if (yy == 4) {
        // bit-pack att_mas: word t covers att[32t..32t+31]; bit j = (att != 0)
        if (i < NWORDS) {
            const float4* src = (const float4*)am + (size_t)i * 8;
            unsigned int m = 0;
#pragma unroll
            for (int j = 0; j < 8; ++j) {
                const float4 v = src[j];
                m |= (v.x != 0.f ? 1u : 0u) << (4 * j);
                m |= (v.y != 0.f ? 1u : 0u) << (4 * j + 1);
                m |= (v.z != 0.f ? 1u : 0u) << (4 * j + 2);
                m |= (v.w != 0.f ? 1u : 0u) << (4 * j + 3);
            }
            mb[i] = m;
        }
        return;
    }
    if (yy == 3) {
        const int wn4 = DMODEL * DMODEL / 4;          // 65536 float4 per weight
        if (i < 4 * wn4) {
            const int w = i >> 16;
            const float* src = (w == 0) ? wq : (w == 1) ? wk : (w == 2) ? wv : wo;
            const float4 v = ((const float4*)src)[i & (wn4 - 1)];
            ushort4 o;
            o.x = f2bf(v.x); o.y = f2bf(v.y); o.z = f2bf(v.z); o.w = f2bf(v.w);
            ((ushort4*)wdst)[i] = o;
        }
        return;
    }
    const float* src = (yy == 0) ? a : (yy == 1) ? b : c;
    ushort_t* d = dst + (size_t)yy * ((size_t)n4 * 4);
    const float4 v = ((const float4*)src)[i];
    ushort4 o;
    o.x = f2bf(v.x); o.y = f2bf(v.y); o.z = f2bf(v.z); o.w = f2bf(v.w);
    ((ushort4*)d)[i] = o;
}

// ---------------- fused projection GEMM (Q/K/V via blockIdx.z) ----------------
__global__ __launch_bounds__(256) void gemm_proj(const ushort_t* __restrict__ Xall,
                                                 const ushort_t* __restrict__ Wall,
                                                 const float* __restrict__ qmas,
                                                 const float* __restrict__ kmas,
                                                 ushort_t* __restrict__ Qh,
                                                 ushort_t* __restrict__ Kh,
                                                 ushort_t* __restrict__ Vt) {
    __shared__ ushort_t As[128 * 32];
    __shared__ ushort_t Bs[128 * 32];
    const int z = blockIdx.z;
    const ushort_t* X  = Xall + (size_t)z * MROWS * DMODEL;
    const ushort_t* Wb = Wall + (size_t)z * DMODEL * DMODEL;
    const float* rowmask = (z == 0) ? qmas : kmas;

    const int tid  = threadIdx.x;
    const int wave = tid >> 6;
    const int lane = tid & 63;
    const int l16  = lane & 15;
    const int quad = lane >> 4;
    const int wr   = wave >> 1;
    const int wc   = wave & 1;
    const int m0   = blockIdx.x * 128;
    const int n0   = blockIdx.y * 128;
    const int crow = lane >> 2;
    const int koff = (lane & 3) * 8;

    floatx4 acc[4][4];
#pragma unroll
    for (int t = 0; t < 4; ++t)
#pragma unroll
        for (int u = 0; u < 4; ++u) acc[t][u] = (floatx4){0.f, 0.f, 0.f, 0.f};

    for (int k0 = 0; k0 < DMODEL; k0 += 32) {
#pragma unroll
        for (int c2 = 0; c2 < 2; ++c2) {
            const int c = wave * 2 + c2;
            gld16(X  + (size_t)(m0 + c * 16 + crow) * DMODEL + k0 + koff, &As[c * 512]);
            gld16(Wb + (size_t)(n0 + c * 16 + crow) * DMODEL + k0 + koff, &Bs[c * 512]);
        }
        __syncthreads();
        short8 a[4], b[4];
#pragma unroll
        for (int t = 0; t < 4; ++t)
            a[t] = *(const short8*)&As[(wr * 64 + t * 16 + l16) * 32 + quad * 8];
#pragma unroll
        for (int u = 0; u < 4; ++u)
            b[u] = *(const short8*)&Bs[(wc * 64 + u * 16 + l16) * 32 + quad * 8];
#pragma unroll
        for (int t = 0; t < 4; ++t)
#pragma unroll
            for (int u = 0; u < 4; ++u) acc[t][u] = mfma_bf16(a[t], b[u], acc[t][u]);
        __syncthreads();
    }

    float rm[4][4];
#pragma unroll
    for (int t = 0; t < 4; ++t)
#pragma unroll
        for (int r = 0; r < 4; ++r)
            rm[t][r] = rowmask[m0 + wr * 64 + t * 16 + quad * 4 + r];
    if (z == 0) {
        // fold log2(e)/sqrt(dk) into Qh so attn uses exp2(S) directly
#pragma unroll
        for (int t = 0; t < 4; ++t)
#pragma unroll
            for (int r = 0; r < 4; ++r) rm[t][r] *= 0.18033688011112042f;
    }

    const int bb    = m0 >> 11;
    const int nbase = (m0 & (NSEQ - 1)) + wr * 64;
#pragma unroll
    for (int t = 0; t < 4; ++t) {
#pragma unroll
        for (int u = 0; u < 4; ++u) {
            const int d = n0 + wc * 64 + u * 16 + l16;
            const int h = d >> 6, cc = d & 63;
            if (z < 2) {
                ushort_t* dst = (z == 0) ? Qh : Kh;
#pragma unroll
                for (int r = 0; r < 4; ++r) {
                    const int n = nbase + t * 16 + quad * 4 + r;
                    dst[((size_t)(bb * NH + h) * NSEQ + n) * DKH + cc] =
                        f2bf(acc[t][u][r] * rm[t][r]);
                }
            } else {
                ushort4 pk;
                pk.x = f2bf(acc[t][u][0] * rm[t][0]);
                pk.y = f2bf(acc[t][u][1] * rm[t][1]);
                pk.z = f2bf(acc[t][u][2] * rm[t][2]);
                pk.w = f2bf(acc[t][u][3] * rm[t][3]);
                const int n = nbase + t * 16 + quad * 4;
                *(ushort4*)(Vt + ((size_t)(bb * NH + h) * DKH + cc) * NSEQ + n) = pk;
            }
        }
    }
}

// ---------------- output GEMM ----------------
__global__ __launch_bounds__(256) void gemm_out(const ushort_t* __restrict__ X,
                                                const ushort_t* __restrict__ Wb,
                                                const float* __restrict__ rowmask,
                                                float* __restrict__ dst) {
    __shared__ ushort_t As[128 * 32];
    __shared__ ushort_t Bs[128 * 32];
    const int tid  = threadIdx.x;
    const int wave = tid >> 6;
    const int lane = tid & 63;
    const int l16  = lane & 15;
    const int quad = lane >> 4;
    const int wr   = wave >> 1;
    const int wc   = wave & 1;
    const int m0   = blockIdx.x * 128;
    const int n0   = blockIdx.y * 128;
    const int crow = lane >> 2;
    const int koff = (lane & 3) * 8;

    floatx4 acc[4][4];
#pragma unroll
    for (int t = 0; t < 4; ++t)
#pragma unroll
        for (int u = 0; u < 4; ++u) acc[t][u] = (floatx4){0.f, 0.f, 0.f, 0.f};

    for (int k0 = 0; k0 < DMODEL; k0 += 32) {
#pragma unroll
        for (int c2 = 0; c2 < 2; ++c2) {
            const int c = wave * 2 + c2;
            gld16(X  + (size_t)(m0 + c * 16 + crow) * DMODEL + k0 + koff, &As[c * 512]);
            gld16(Wb + (size_t)(n0 + c * 16 + crow) * DMODEL + k0 + koff, &Bs[c * 512]);
        }
        __syncthreads();
        short8 a[4], b[4];
#pragma unroll
        for (int t = 0; t < 4; ++t)
            a[t] = *(const short8*)&As[(wr * 64 + t * 16 + l16) * 32 + quad * 8];
#pragma unroll
        for (int u = 0; u < 4; ++u)
            b[u] = *(const short8*)&Bs[(wc * 64 + u * 16 + l16) * 32 + quad * 8];
#pragma unroll
        for (int t = 0; t < 4; ++t)
#pragma unroll
            for (int u = 0; u < 4; ++u) acc[t][u] = mfma_bf16(a[t], b[u], acc[t][u]);
        __syncthreads();
    }

#pragma unroll
    for (int t = 0; t < 4; ++t) {
#pragma unroll
        for (int r = 0; r < 4; ++r) {
            const int m = m0 + wr * 64 + t * 16 + quad * 4 + r;
            const float rm = rowmask[m];
#pragma unroll
            for (int u = 0; u < 4; ++u) {
                const int d = n0 + wc * 64 + u * 16 + l16;
                dst[(size_t)m * DMODEL + d] = acc[t][u][r] * rm;
            }
        }
    }
}

// ---------------- flash attention: K via pinned 4-deep reg pipeline, V in LDS ----------------
// Qh (pre-scaled by log2e/8), Kh: [b][h][n][64] bf16;  Vt: [b][h][c][n] bf16;
// Mb: bit-packed att_mas (in d_out, overwritten later by gemm_out); kmas fp32.
// S computed TRANSPOSED (mfma(K,Q)): lane (l16,quad) reg r holds S[key][q=l16].
// K fragment layout == row-major Kh: asm global_load_dwordx4, 4 frags in flight,
// counted vmcnt waits (regs tied through the wait so MFMA can't hoist).
// Barriers are lgkm-only: V/mask prefetch stays in flight across them.
__global__ __launch_bounds__(256) void attn_kernel(const ushort_t* __restrict__ Qh,
                                                   const ushort_t* __restrict__ Kh,
                                                   const ushort_t* __restrict__ Vt,
                                                   const unsigned int* __restrict__ Mb,
                                                   const float* __restrict__ kmas,
                                                   ushort_t* __restrict__ y) {
    __shared__ __align__(16) ushort_t Vs[64 * 136];      // 17408 B
    __shared__ __align__(16) ushort_t Ps[4][16 * 136];   // 17408 B (total 34816)

    const int tid  = threadIdx.x;
    const int wave = tid >> 6;
    const int lane = tid & 63;
    const int l16  = lane & 15;
    const int quad = lane >> 4;
    const int h    = blockIdx.y;
    const int b    = blockIdx.z;
    const int qw   = blockIdx.x * 64 + wave * 16;   // this wave's 16 q-rows

    ushort_t* Psw = Ps[wave];

    const ushort_t* Kb = Kh + (size_t)(b * NH + h) * NSEQ * DKH;
    const ushort_t* Vb = Vt + (size_t)(b * NH + h) * DKH * NSEQ;
    // per-lane mask row: q = qw + l16 (S^T layout puts one q-row per lane)
    const uint4* Mv = (const uint4*)(Mb + ((size_t)(b * NSEQ + qw) + l16) * NW32);

    const ushort_t* Qp = Qh + ((size_t)((b * NH + h) * NSEQ) + qw + l16) * DKH + quad * 8;
    const short8 qfa = *(const short8*)Qp;
    const short8 qfb = *(const short8*)(Qp + 32);

    // per-lane K fragment base: row (l16), col (quad*8)
    const ushort_t* Kfrag = Kb + (size_t)l16 * DKH + quad * 8;

    float lpart = 0.f;      // sum of P over this lane's 32 keys of row q=qw+l16
    floatx4 accO[4];
#pragma unroll
    for (int ct = 0; ct < 4; ++ct) accO[ct] = (floatx4){0.f, 0.f, 0.f, 0.f};

    // ---- prologue: issue tile-0 V staging + mask ----
    short8 vv[4];
    uint4 mwn;
#pragma unroll
    for (int i = 0; i < 4; ++i) {
        const int c = tid + i * 256;
        vv[i] = *(const short8*)(Vb + (size_t)(c >> 4) * NSEQ + (c & 15) * 8);
    }
    mwn = Mv[0];

    short8 kslot[4][2];   // 4-deep K fragment rotation (all indices compile-time)

#define KSTEP(FR, VM) do {                                                         \
    KWAIT(VM, kslot[(FR) & 3][0], kslot[(FR) & 3][1]);                             \
    floatx4 s = {0.f, 0.f, 0.f, 0.f};                                              \
    s = mfma_bf16(kslot[(FR) & 3][0], qfa, s);                                     \
    s = mfma_bf16(kslot[(FR) & 3][1], qfb, s);                                     \
    if ((FR) + 4 < 8) {                                                            \
        const ushort_t* kp_ = Kt + (size_t)((FR) + 4) * 16 * DKH;                  \
        KLOAD(kslot[(FR) & 3][0], kp_);                                            \
        KLOAD(kslot[(FR) & 3][1], kp_ + 32);                                       \
    }                                                                              \
    const unsigned int w_ = wsh[(FR) >> 1];                                        \
    float p_[4];                                                                   \
    _Pragma("unroll")                                                              \
    for (int r = 0; r < 4; ++r) {                                                  \
        const int bitp = (((FR) & 1) << 4) + r;                                    \
        const unsigned int mm =                                                    \
            (unsigned int)__builtin_amdgcn_sbfe((int)w_, bitp, 1);                 \
        const unsigned int pb =                                                    \
            __builtin_bit_cast(unsigned int, exp2f(s[r])) & mm;                    \
        p_[r] = __builtin_bit_cast(float, pb);                                     \
        lpart += p_[r];                                                            \
    }                                                                              \
    uint2 pk_;                                                                     \
    pk_.x = cvt_pk_bf16(p_[0], p_[1]);                                             \
    pk_.y = cvt_pk_bf16(p_[2], p_[3]);                                             \
    *(uint2*)&Psw[l16 * 136 + (FR) * 16 + quad * 4] = pk_;                         \
} while (0)

    for (int kt = 0; kt < NSEQ / 128; ++kt) {
        const int k0 = kt * 128;

        lgkm_barrier();   // (a) previous tile's Vs/Ps reads complete (LDS only)
        // consume mask NOW (before K issues) so its vmcnt wait can't drain K pipe
        const uint4 mw = mwn;
        const unsigned int wsh[4] = {mw.x >> (quad * 4), mw.y >> (quad * 4),
                                     mw.z >> (quad * 4), mw.w >> (quad * 4)};
#pragma unroll
        for (int i = 0; i < 4; ++i) {
            const int c = tid + i * 256;
            *(short8*)&Vs[(c >> 4) * 136 + (c & 15) * 8] = vv[i];
        }
        lgkm_barrier();   // (b) Vs staged (LDS only; K loads unaffected)

        // ---- issue K frags 0..3, then pipelined S + softmax ----
        const ushort_t* Kt = Kfrag + (size_t)k0 * DKH;
        KLOAD(kslot[0][0], Kt);
        KLOAD(kslot[0][1], Kt + 32);
        KLOAD(kslot[1][0], Kt + 1 * 16 * DKH);
        KLOAD(kslot[1][1], Kt + 1 * 16 * DKH + 32);
        KLOAD(kslot[2][0], Kt + 2 * 16 * DKH);
        KLOAD(kslot[2][1], Kt + 2 * 16 * DKH + 32);
        KLOAD(kslot[3][0], Kt + 3 * 16 * DKH);
        KLOAD(kslot[3][1], Kt + 3 * 16 * DKH + 32);

        KSTEP(0, 6);
        KSTEP(1, 6);
        KSTEP(2, 6);
        KSTEP(3, 6);
        KSTEP(4, 6);
        KSTEP(5, 4);
        KSTEP(6, 2);
        KSTEP(7, 0);

        // ---- issue next tile's V + mask (in flight across PV and barrier (a)) ----
        if (kt + 1 < NSEQ / 128) {
            const int kn = k0 + 128;
#pragma unroll
            for (int i = 0; i < 4; ++i) {
                const int c = tid + i * 256;
                vv[i] = *(const short8*)(Vb + (size_t)(c >> 4) * NSEQ + kn + (c & 15) * 8);
            }
            mwn = Mv[kt + 1];
        }

        __builtin_amdgcn_wave_barrier();  // LDS W->R order (wave-local, in-order DS pipe)
        short8 pf[4];
#pragma unroll
        for (int kf = 0; kf < 4; ++kf)
            pf[kf] = *(const short8*)&Psw[l16 * 136 + kf * 32 + quad * 8];
        __builtin_amdgcn_wave_barrier();

        // ---- O += P.V ----
#pragma unroll
        for (int ct = 0; ct < 4; ++ct) {
#pragma unroll
            for (int kf = 0; kf < 4; ++kf) {
                const short8 vb = *(const short8*)&Vs[(ct * 16 + l16) * 136 + kf * 32 + quad * 8];
                accO[ct] = mfma_bf16(pf[kf], vb, accO[ct]);
            }
        }
    }
#undef KSTEP

    // ---- epilogue: reduce l across quads, normalize, post-mask, store ----
    float lfull = lpart;
    lfull += __shfl_xor(lfull, 16);
    lfull += __shfl_xor(lfull, 32);   // lane holds full l for q-row (qw + l16)
#pragma unroll
    for (int r = 0; r < 4; ++r) {
        const int q = qw + quad * 4 + r;
        const float l = __shfl(lfull, quad * 4 + r);  // l of row (qw + quad*4 + r)
        const float scale = kmas[b * NSEQ + q] / l;
#pragma unroll
        for (int ct = 0; ct < 4; ++ct) {
            y[(size_t)(b * NSEQ + q) * DMODEL + h * DKH + ct * 16 + l16] =
                f2bf(accO[ct][r] * scale);
        }
    }
}

extern "C" void kernel_launch(void* const* d_in, const int* in_sizes, int n_in,
                              void* d_out, int out_size, void* d_ws, size_t ws_size,
                              hipStream_t stream) {
    (void)in_sizes; (void)n_in; (void)out_size; (void)ws_size;
    const float* Q  = (const float*)d_in[0];
    const float* K  = (const float*)d_in[1];
    const float* V  = (const float*)d_in[2];
    const float* qm = (const float*)d_in[3];
    const float* km = (const float*)d_in[4];
    const float* am = (const float*)d_in[5];
    const float* WQ = (const float*)d_in[6];
    const float* WK = (const float*)d_in[7];
    const float* WV = (const float*)d_in[8];
    const float* WO = (const float*)d_in[9];

    const size_t XN = (size_t)MROWS * DMODEL;        // 4,194,304
    const size_t WN = (size_t)DMODEL * DMODEL;       // 262,144
    ushort_t* Xbf = (ushort_t*)d_ws;                 // Q,K,V bf16: 3*XN
    ushort_t* Wbf = Xbf + 3 * XN;                    // WQ,WK,WV,WO bf16: 4*WN
    ushort_t* WOb = Wbf + 3 * WN;
    ushort_t* Qh  = Wbf + 4 * WN;
    ushort_t* Kh  = Qh + XN;
    ushort_t* Vt  = Kh + XN;
    ushort_t* y   = Vt + XN;
    // packed mask lives in d_out (2 MB of 16 MB); gemm_out fully overwrites d_out afterwards
    unsigned int* Mbits = (unsigned int*)d_out;
    float* out = (float*)d_out;

    hipLaunchKernelGGL(cvt_all, dim3(4096, 5), dim3(256), 0, stream,
                       Q, K, V, WQ, WK, WV, WO, am, Xbf, Wbf, Mbits, (int)(XN / 4));

    hipLaunchKernelGGL(gemm_proj, dim3(MROWS / 128, DMODEL / 128, 3), dim3(256), 0, stream,
                       Xbf, Wbf, qm, km, Qh, Kh, Vt);

    hipLaunchKernelGGL(attn_kernel, dim3(NSEQ / 64, NH, BS_), dim3(256), 0, stream,
                       Qh, Kh, Vt, Mbits, km, y);

    hipLaunchKernelGGL(gemm_out, dim3(MROWS / 128, DMODEL / 128), dim3(256), 0, stream,
                       y, WOb, km, out);
}

// Round 6
// 291.022 us; speedup vs baseline: 1.2202x; 1.2202x over previous
//
#include <hip/hip_runtime.h>

// MultiHeadAttention: BS=4, N=2048, D=512, H=8, DK=64. fp32 in/out, bf16 MFMA compute.
// Round 11: re-anchor on the proven R6 attn structure (K+V staged in LDS, separate
// wave-private Ps, two __syncthreads per tile) and add ONLY the isolated win from
// the R7 experiment: next-tile K/V/mask loads issued right after barrier (b), so
// their latency hides under S+softmax+PV instead of being exposed at barrier (a).
// Softmax fused per-fragment (low reg liveness). cvt_all = QKV + weights + mask pack.

#define BS_    4
#define NSEQ   2048
#define DMODEL 512
#define NH     8
#define DKH    64
#define MROWS  (BS_ * NSEQ)   // 8192
#define NW32   (NSEQ / 32)    // 64 mask words per row
#define NWORDS (BS_ * NSEQ * NSEQ / 32)  // 524288 packed mask words

typedef unsigned short ushort_t;
typedef __attribute__((ext_vector_type(8))) short short8;   // 8 bf16 (4 VGPRs)
typedef __attribute__((ext_vector_type(4))) float floatx4;  // 4 fp32 acc

__device__ __forceinline__ ushort_t f2bf(float f) {
    unsigned int x = __builtin_bit_cast(unsigned int, f);
    unsigned int lsb = (x >> 16) & 1u;
    x += 0x7fffu + lsb;          // round-to-nearest-even
    return (ushort_t)(x >> 16);
}
__device__ __forceinline__ floatx4 mfma_bf16(short8 a, short8 b, floatx4 c) {
    return __builtin_amdgcn_mfma_f32_16x16x32_bf16(a, b, c, 0, 0, 0);
}
__device__ __forceinline__ void gld16(const ushort_t* g, ushort_t* l) {
    __builtin_amdgcn_global_load_lds(
        (const __attribute__((address_space(1))) unsigned int*)g,
        (__attribute__((address_space(3))) unsigned int*)l, 16, 0, 0);
}
__device__ __forceinline__ unsigned int cvt_pk_bf16(float lo, float hi) {
    unsigned int r;
    asm("v_cvt_pk_bf16_f32 %0, %1, %2" : "=v"(r) : "v"(lo), "v"(hi));
    return r;
}

// ---------------- fp32 -> bf16 converts + weights + att_mas bit-pack ----------------
// grid (4096, 5): y=0..2 QKV slices; y=3 weights (WQ,WK,WV,WO contiguous); y=4 mask
__global__ __launch_bounds__(256) void cvt_all(const float* __restrict__ a,
                                               const float* __restrict__ b,
                                               const float* __restrict__ c,
                                               const float* __restrict__ wq,
                                               const float* __restrict__ wk,
                                               const float* __restrict__ wv,
                                               const float* __restrict__ wo,
                                               const float* __restrict__ am,
                                               ushort_t* __restrict__ dst,
                                               ushort_t* __restrict__ wdst,
                                               unsigned int* __restrict__ mb, int n4) {
    const int i = blockIdx.x * blockDim.x + threadIdx.x;
    const int yy = blockIdx.y;
    if (yy == 4) {
        // bit-pack att_mas: word t covers att[32t..32t+31]; bit j = (att != 0)
        if (i < NWORDS) {
            const float4* src = (const float4*)am + (size_t)i * 8;
            unsigned int m = 0;
#pragma unroll
            for (int j = 0; j < 8; ++j) {
                const float4 v = src[j];
                m |= (v.x != 0.f ? 1u : 0u) << (4 * j);
                m |= (v.y != 0.f ? 1u : 0u) << (4 * j + 1);
                m |= (v.z != 0.f ? 1u : 0u) << (4 * j + 2);
                m |= (v.w != 0.f ? 1u : 0u) << (4 * j + 3);
            }
            mb[i] = m;
        }
        return;
    }
    if (yy == 3) {
        const int wn4 = DMODEL * DMODEL / 4;          // 65536 float4 per weight
        if (i < 4 * wn4) {
            const int w = i >> 16;
            const float* src = (w == 0) ? wq : (w == 1) ? wk : (w == 2) ? wv : wo;
            const float4 v = ((const float4*)src)[i & (wn4 - 1)];
            ushort4 o;
            o.x = f2bf(v.x); o.y = f2bf(v.y); o.z = f2bf(v.z); o.w = f2bf(v.w);
            ((ushort4*)wdst)[i] = o;
        }
        return;
    }
    const float* src = (yy == 0) ? a : (yy == 1) ? b : c;
    ushort_t* d = dst + (size_t)yy * ((size_t)n4 * 4);
    const float4 v = ((const float4*)src)[i];
    ushort4 o;
    o.x = f2bf(v.x); o.y = f2bf(v.y); o.z = f2bf(v.z); o.w = f2bf(v.w);
    ((ushort4*)d)[i] = o;
}

// ---------------- fused projection GEMM (Q/K/V via blockIdx.z) ----------------
__global__ __launch_bounds__(256) void gemm_proj(const ushort_t* __restrict__ Xall,
                                                 const ushort_t* __restrict__ Wall,
                                                 const float* __restrict__ qmas,
                                                 const float* __restrict__ kmas,
                                                 ushort_t* __restrict__ Qh,
                                                 ushort_t* __restrict__ Kh,
                                                 ushort_t* __restrict__ Vt) {
    __shared__ ushort_t As[128 * 32];
    __shared__ ushort_t Bs[128 * 32];
    const int z = blockIdx.z;
    const ushort_t* X  = Xall + (size_t)z * MROWS * DMODEL;
    const ushort_t* Wb = Wall + (size_t)z * DMODEL * DMODEL;
    const float* rowmask = (z == 0) ? qmas : kmas;

    const int tid  = threadIdx.x;
    const int wave = tid >> 6;
    const int lane = tid & 63;
    const int l16  = lane & 15;
    const int quad = lane >> 4;
    const int wr   = wave >> 1;
    const int wc   = wave & 1;
    const int m0   = blockIdx.x * 128;
    const int n0   = blockIdx.y * 128;
    const int crow = lane >> 2;
    const int koff = (lane & 3) * 8;

    floatx4 acc[4][4];
#pragma unroll
    for (int t = 0; t < 4; ++t)
#pragma unroll
        for (int u = 0; u < 4; ++u) acc[t][u] = (floatx4){0.f, 0.f, 0.f, 0.f};

    for (int k0 = 0; k0 < DMODEL; k0 += 32) {
#pragma unroll
        for (int c2 = 0; c2 < 2; ++c2) {
            const int c = wave * 2 + c2;
            gld16(X  + (size_t)(m0 + c * 16 + crow) * DMODEL + k0 + koff, &As[c * 512]);
            gld16(Wb + (size_t)(n0 + c * 16 + crow) * DMODEL + k0 + koff, &Bs[c * 512]);
        }
        __syncthreads();
        short8 a[4], b[4];
#pragma unroll
        for (int t = 0; t < 4; ++t)
            a[t] = *(const short8*)&As[(wr * 64 + t * 16 + l16) * 32 + quad * 8];
#pragma unroll
        for (int u = 0; u < 4; ++u)
            b[u] = *(const short8*)&Bs[(wc * 64 + u * 16 + l16) * 32 + quad * 8];
#pragma unroll
        for (int t = 0; t < 4; ++t)
#pragma unroll
            for (int u = 0; u < 4; ++u) acc[t][u] = mfma_bf16(a[t], b[u], acc[t][u]);
        __syncthreads();
    }

    float rm[4][4];
#pragma unroll
    for (int t = 0; t < 4; ++t)
#pragma unroll
        for (int r = 0; r < 4; ++r)
            rm[t][r] = rowmask[m0 + wr * 64 + t * 16 + quad * 4 + r];
    if (z == 0) {
        // fold log2(e)/sqrt(dk) into Qh so attn uses exp2(S) directly
#pragma unroll
        for (int t = 0; t < 4; ++t)
#pragma unroll
            for (int r = 0; r < 4; ++r) rm[t][r] *= 0.18033688011112042f;
    }

    const int bb    = m0 >> 11;
    const int nbase = (m0 & (NSEQ - 1)) + wr * 64;
#pragma unroll
    for (int t = 0; t < 4; ++t) {
#pragma unroll
        for (int u = 0; u < 4; ++u) {
            const int d = n0 + wc * 64 + u * 16 + l16;
            const int h = d >> 6, cc = d & 63;
            if (z < 2) {
                ushort_t* dst = (z == 0) ? Qh : Kh;
#pragma unroll
                for (int r = 0; r < 4; ++r) {
                    const int n = nbase + t * 16 + quad * 4 + r;
                    dst[((size_t)(bb * NH + h) * NSEQ + n) * DKH + cc] =
                        f2bf(acc[t][u][r] * rm[t][r]);
                }
            } else {
                ushort4 pk;
                pk.x = f2bf(acc[t][u][0] * rm[t][0]);
                pk.y = f2bf(acc[t][u][1] * rm[t][1]);
                pk.z = f2bf(acc[t][u][2] * rm[t][2]);
                pk.w = f2bf(acc[t][u][3] * rm[t][3]);
                const int n = nbase + t * 16 + quad * 4;
                *(ushort4*)(Vt + ((size_t)(bb * NH + h) * DKH + cc) * NSEQ + n) = pk;
            }
        }
    }
}

// ---------------- output GEMM ----------------
__global__ __launch_bounds__(256) void gemm_out(const ushort_t* __restrict__ X,
                                                const ushort_t* __restrict__ Wb,
                                                const float* __restrict__ rowmask,
                                                float* __restrict__ dst) {
    __shared__ ushort_t As[128 * 32];
    __shared__ ushort_t Bs[128 * 32];
    const int tid  = threadIdx.x;
    const int wave = tid >> 6;
    const int lane = tid & 63;
    const int l16  = lane & 15;
    const int quad = lane >> 4;
    const int wr   = wave >> 1;
    const int wc   = wave & 1;
    const int m0   = blockIdx.x * 128;
    const int n0   = blockIdx.y * 128;
    const int crow = lane >> 2;
    const int koff = (lane & 3) * 8;

    floatx4 acc[4][4];
#pragma unroll
    for (int t = 0; t < 4; ++t)
#pragma unroll
        for (int u = 0; u < 4; ++u) acc[t][u] = (floatx4){0.f, 0.f, 0.f, 0.f};

    for (int k0 = 0; k0 < DMODEL; k0 += 32) {
#pragma unroll
        for (int c2 = 0; c2 < 2; ++c2) {
            const int c = wave * 2 + c2;
            gld16(X  + (size_t)(m0 + c * 16 + crow) * DMODEL + k0 + koff, &As[c * 512]);
            gld16(Wb + (size_t)(n0 + c * 16 + crow) * DMODEL + k0 + koff, &Bs[c * 512]);
        }
        __syncthreads();
        short8 a[4], b[4];
#pragma unroll
        for (int t = 0; t < 4; ++t)
            a[t] = *(const short8*)&As[(wr * 64 + t * 16 + l16) * 32 + quad * 8];
#pragma unroll
        for (int u = 0; u < 4; ++u)
            b[u] = *(const short8*)&Bs[(wc * 64 + u * 16 + l16) * 32 + quad * 8];
#pragma unroll
        for (int t = 0; t < 4; ++t)
#pragma unroll
            for (int u = 0; u < 4; ++u) acc[t][u] = mfma_bf16(a[t], b[u], acc[t][u]);
        __syncthreads();
    }

#pragma unroll
    for (int t = 0; t < 4; ++t) {
#pragma unroll
        for (int r = 0; r < 4; ++r) {
            const int m = m0 + wr * 64 + t * 16 + quad * 4 + r;
            const float rm = rowmask[m];
#pragma unroll
            for (int u = 0; u < 4; ++u) {
                const int d = n0 + wc * 64 + u * 16 + l16;
                dst[(size_t)m * DMODEL + d] = acc[t][u][r] * rm;
            }
        }
    }
}

// ---------------- flash attention: 64-q blocks, LDS-staged 128-key tiles ----------------
// Qh (pre-scaled by log2e/8), Kh: [b][h][n][64] bf16;  Vt: [b][h][c][n] bf16;
// Mb: bit-packed att_mas (in d_out, overwritten later by gemm_out); kmas fp32.
// S computed TRANSPOSED (mfma(K,Q)): lane (l16,quad) reg r holds S[key][q=l16].
// Next tile's K/V/mask loads issued right after barrier (b): regs are dead in that
// window and the ~500cy latency hides under S+softmax+PV, so barrier (a)'s vmcnt
// drain costs nothing. Softmax fused per-fragment. LDS 53248 B, 2 barriers/tile.
__global__ __launch_bounds__(256) void attn_kernel(const ushort_t* __restrict__ Qh,
                                                   const ushort_t* __restrict__ Kh,
                                                   const ushort_t* __restrict__ Vt,
                                                   const unsigned int* __restrict__ Mb,
                                                   const float* __restrict__ kmas,
                                                   ushort_t* __restrict__ y) {
    __shared__ __align__(16) ushort_t Ks[128 * 72];      // 18432 B
    __shared__ __align__(16) ushort_t Vs[64 * 136];      // 17408 B
    __shared__ __align__(16) ushort_t Ps[4][16 * 136];   // 17408 B (total 53248)

    const int tid  = threadIdx.x;
    const int wave = tid >> 6;
    const int lane = tid & 63;
    const int l16  = lane & 15;
    const int quad = lane >> 4;
    const int h    = blockIdx.y;
    const int b    = blockIdx.z;
    const int qw   = blockIdx.x * 64 + wave * 16;   // this wave's 16 q-rows

    ushort_t* Psw = Ps[wave];

    const ushort_t* Kb = Kh + (size_t)(b * NH + h) * NSEQ * DKH;
    const ushort_t* Vb = Vt + (size_t)(b * NH + h) * DKH * NSEQ;
    // per-lane mask row: q = qw + l16 (S^T layout puts one q-row per lane)
    const uint4* Mv = (const uint4*)(Mb + ((size_t)(b * NSEQ + qw) + l16) * NW32);

    const ushort_t* Qp = Qh + ((size_t)((b * NH + h) * NSEQ) + qw + l16) * DKH + quad * 8;
    const short8 qfa = *(const short8*)Qp;
    const short8 qfb = *(const short8*)(Qp + 32);

    float lpart = 0.f;      // sum of P over this lane's 32 keys of row q=qw+l16
    floatx4 accO[4];
#pragma unroll
    for (int ct = 0; ct < 4; ++ct) accO[ct] = (floatx4){0.f, 0.f, 0.f, 0.f};

    // ---- prologue: issue tile-0 staging loads + mask ----
    short8 kv[4], vv[4];
    uint4 mwn;
#pragma unroll
    for (int i = 0; i < 4; ++i) {
        const int c = tid + i * 256;
        kv[i] = *(const short8*)(Kb + (size_t)(c >> 3) * DKH + (c & 7) * 8);
    }
#pragma unroll
    for (int i = 0; i < 4; ++i) {
        const int c = tid + i * 256;
        vv[i] = *(const short8*)(Vb + (size_t)(c >> 4) * NSEQ + (c & 15) * 8);
    }
    mwn = Mv[0];

    for (int kt = 0; kt < NSEQ / 128; ++kt) {
        const uint4 mw = mwn;

        __syncthreads();   // (a) previous tile's LDS reads done; kv/vv drained (needed now)
#pragma unroll
        for (int i = 0; i < 4; ++i) {
            const int c = tid + i * 256;
            *(short8*)&Ks[(c >> 3) * 72 + (c & 7) * 8] = kv[i];
        }
#pragma unroll
        for (int i = 0; i < 4; ++i) {
            const int c = tid + i * 256;
            *(short8*)&Vs[(c >> 4) * 136 + (c & 15) * 8] = vv[i];
        }
        __syncthreads();   // (b) tile staged; kv/vv regs now dead

        // ---- prefetch next tile (latency hides under S + softmax + PV) ----
        if (kt + 1 < NSEQ / 128) {
            const int kn = (kt + 1) * 128;
#pragma unroll
            for (int i = 0; i < 4; ++i) {
                const int c = tid + i * 256;
                kv[i] = *(const short8*)(Kb + (size_t)(kn + (c >> 3)) * DKH + (c & 7) * 8);
            }
#pragma unroll
            for (int i = 0; i < 4; ++i) {
                const int c = tid + i * 256;
                vv[i] = *(const short8*)(Vb + (size_t)(c >> 4) * NSEQ + kn + (c & 15) * 8);
            }
            mwn = Mv[kt + 1];
        }

        // ---- fused S^T + softmax per 16-key fragment ----
        const unsigned int wsh[4] = {mw.x >> (quad * 4), mw.y >> (quad * 4),
                                     mw.z >> (quad * 4), mw.w >> (quad * 4)};
#pragma unroll
        for (int fr = 0; fr < 8; ++fr) {
            const short8 ka = *(const short8*)&Ks[(fr * 16 + l16) * 72 + quad * 8];
            const short8 kb = *(const short8*)&Ks[(fr * 16 + l16) * 72 + 32 + quad * 8];
            floatx4 s = {0.f, 0.f, 0.f, 0.f};
            s = mfma_bf16(ka, qfa, s);
            s = mfma_bf16(kb, qfb, s);
            float p[4];
#pragma unroll
            for (int r = 0; r < 4; ++r) {
                const int bitp = ((fr & 1) << 4) + r;
                const unsigned int mm =
                    (unsigned int)__builtin_amdgcn_sbfe((int)wsh[fr >> 1], bitp, 1);
                const float e = exp2f(s[r]);
                const unsigned int pb = __builtin_bit_cast(unsigned int, e) & mm;
                p[r] = __builtin_bit_cast(float, pb);
                lpart += p[r];
            }
            uint2 pk;
            pk.x = cvt_pk_bf16(p[0], p[1]);
            pk.y = cvt_pk_bf16(p[2], p[3]);
            *(uint2*)&Psw[l16 * 136 + fr * 16 + quad * 4] = pk;
        }

        __builtin_amdgcn_wave_barrier();  // LDS W->R order (wave-local, in-order DS pipe)
        short8 pf[4];
#pragma unroll
        for (int kf = 0; kf < 4; ++kf)
            pf[kf] = *(const short8*)&Psw[l16 * 136 + kf * 32 + quad * 8];
        __builtin_amdgcn_wave_barrier();

        // ---- O += P.V ----
#pragma unroll
        for (int ct = 0; ct < 4; ++ct) {
#pragma unroll
            for (int kf = 0; kf < 4; ++kf) {
                const short8 vb = *(const short8*)&Vs[(ct * 16 + l16) * 136 + kf * 32 + quad * 8];
                accO[ct] = mfma_bf16(pf[kf], vb, accO[ct]);
            }
        }
    }

    // ---- epilogue: reduce l across quads, normalize, post-mask, store ----
    float lfull = lpart;
    lfull += __shfl_xor(lfull, 16);
    lfull += __shfl_xor(lfull, 32);   // lane holds full l for q-row (qw + l16)
#pragma unroll
    for (int r = 0; r < 4; ++r) {
        const int q = qw + quad * 4 + r;
        const float l = __shfl(lfull, quad * 4 + r);  // l of row (qw + quad*4 + r)
        const float scale = kmas[b * NSEQ + q] / l;
#pragma unroll
        for (int ct = 0; ct < 4; ++ct) {
            y[(size_t)(b * NSEQ + q) * DMODEL + h * DKH + ct * 16 + l16] =
                f2bf(accO[ct][r] * scale);
        }
    }
}

extern "C" void kernel_launch(void* const* d_in, const int* in_sizes, int n_in,
                              void* d_out, int out_size, void* d_ws, size_t ws_size,
                              hipStream_t stream) {
    (void)in_sizes; (void)n_in; (void)out_size; (void)ws_size;
    const float* Q  = (const float*)d_in[0];
    const float* K  = (const float*)d_in[1];
    const float* V  = (const float*)d_in[2];
    const float* qm = (const float*)d_in[3];
    const float* km = (const float*)d_in[4];
    const float* am = (const float*)d_in[5];
    const float* WQ = (const float*)d_in[6];
    const float* WK = (const float*)d_in[7];
    const float* WV = (const float*)d_in[8];
    const float* WO = (const float*)d_in[9];

    const size_t XN = (size_t)MROWS * DMODEL;        // 4,194,304
    const size_t WN = (size_t)DMODEL * DMODEL;       // 262,144
    ushort_t* Xbf = (ushort_t*)d_ws;                 // Q,K,V bf16: 3*XN
    ushort_t* Wbf = Xbf + 3 * XN;                    // WQ,WK,WV,WO bf16: 4*WN
    ushort_t* WOb = Wbf + 3 * WN;
    ushort_t* Qh  = Wbf + 4 * WN;
    ushort_t* Kh  = Qh + XN;
    ushort_t* Vt  = Kh + XN;
    ushort_t* y   = Vt + XN;
    // packed mask lives in d_out (2 MB of 16 MB); gemm_out fully overwrites d_out afterwards
    unsigned int* Mbits = (unsigned int*)d_out;
    float* out = (float*)d_out;

    hipLaunchKernelGGL(cvt_all, dim3(4096, 5), dim3(256), 0, stream,
                       Q, K, V, WQ, WK, WV, WO, am, Xbf, Wbf, Mbits, (int)(XN / 4));

    hipLaunchKernelGGL(gemm_proj, dim3(MROWS / 128, DMODEL / 128, 3), dim3(256), 0, stream,
                       Xbf, Wbf, qm, km, Qh, Kh, Vt);

    hipLaunchKernelGGL(attn_kernel, dim3(NSEQ / 64, NH, BS_), dim3(256), 0, stream,
                       Qh, Kh, Vt, Mbits, km, y);

    hipLaunchKernelGGL(gemm_out, dim3(MROWS / 128, DMODEL / 128), dim3(256), 0, stream,
                       y, WOb, km, out);
}

// Round 7
// 281.903 us; speedup vs baseline: 1.2596x; 1.0323x over previous
//
#include <hip/hip_runtime.h>

// MultiHeadAttention: BS=4, N=2048, D=512, H=8, DK=64. fp32 in/out, bf16 MFMA compute.
// Round 12: attn is LDS-pipe-bound (~80% of cycles = DS ops + conflicts; latency
// experiments R7-R10 all null/negative). Fix: 2 q-groups per wave (32 q-rows).
// K fragment read once -> 4 MFMAs (2 groups); V fragment read once -> 2 MFMAs.
// Per-q LDS traffic cut ~45%. Block = 128 q, grid 16x8x4 = 512 = exactly 2/CU.

#define BS_    4
#define NSEQ   2048
#define DMODEL 512
#define NH     8
#define DKH    64
#define MROWS  (BS_ * NSEQ)   // 8192
#define NW32   (NSEQ / 32)    // 64 mask words per row
#define NWORDS (BS_ * NSEQ * NSEQ / 32)  // 524288 packed mask words

typedef unsigned short ushort_t;
typedef __attribute__((ext_vector_type(8))) short short8;   // 8 bf16 (4 VGPRs)
typedef __attribute__((ext_vector_type(4))) float floatx4;  // 4 fp32 acc

__device__ __forceinline__ ushort_t f2bf(float f) {
    unsigned int x = __builtin_bit_cast(unsigned int, f);
    unsigned int lsb = (x >> 16) & 1u;
    x += 0x7fffu + lsb;          // round-to-nearest-even
    return (ushort_t)(x >> 16);
}
__device__ __forceinline__ floatx4 mfma_bf16(short8 a, short8 b, floatx4 c) {
    return __builtin_amdgcn_mfma_f32_16x16x32_bf16(a, b, c, 0, 0, 0);
}
__device__ __forceinline__ void gld16(const ushort_t* g, ushort_t* l) {
    __builtin_amdgcn_global_load_lds(
        (const __attribute__((address_space(1))) unsigned int*)g,
        (__attribute__((address_space(3))) unsigned int*)l, 16, 0, 0);
}
__device__ __forceinline__ unsigned int cvt_pk_bf16(float lo, float hi) {
    unsigned int r;
    asm("v_cvt_pk_bf16_f32 %0, %1, %2" : "=v"(r) : "v"(lo), "v"(hi));
    return r;
}

// ---------------- fp32 -> bf16 converts + weights + att_mas bit-pack ----------------
// grid (4096, 5): y=0..2 QKV slices; y=3 weights (WQ,WK,WV,WO contiguous); y=4 mask
__global__ __launch_bounds__(256) void cvt_all(const float* __restrict__ a,
                                               const float* __restrict__ b,
                                               const float* __restrict__ c,
                                               const float* __restrict__ wq,
                                               const float* __restrict__ wk,
                                               const float* __restrict__ wv,
                                               const float* __restrict__ wo,
                                               const float* __restrict__ am,
                                               ushort_t* __restrict__ dst,
                                               ushort_t* __restrict__ wdst,
                                               unsigned int* __restrict__ mb, int n4) {
    const int i = blockIdx.x * blockDim.x + threadIdx.x;
    const int yy = blockIdx.y;
    if (yy == 4) {
        // bit-pack att_mas: word t covers att[32t..32t+31]; bit j = (att != 0)
        if (i < NWORDS) {
            const float4* src = (const float4*)am + (size_t)i * 8;
            unsigned int m = 0;
#pragma unroll
            for (int j = 0; j < 8; ++j) {
                const float4 v = src[j];
                m |= (v.x != 0.f ? 1u : 0u) << (4 * j);
                m |= (v.y != 0.f ? 1u : 0u) << (4 * j + 1);
                m |= (v.z != 0.f ? 1u : 0u) << (4 * j + 2);
                m |= (v.w != 0.f ? 1u : 0u) << (4 * j + 3);
            }
            mb[i] = m;
        }
        return;
    }
    if (yy == 3) {
        const int wn4 = DMODEL * DMODEL / 4;          // 65536 float4 per weight
        if (i < 4 * wn4) {
            const int w = i >> 16;
            const float* src = (w == 0) ? wq : (w == 1) ? wk : (w == 2) ? wv : wo;
            const float4 v = ((const float4*)src)[i & (wn4 - 1)];
            ushort4 o;
            o.x = f2bf(v.x); o.y = f2bf(v.y); o.z = f2bf(v.z); o.w = f2bf(v.w);
            ((ushort4*)wdst)[i] = o;
        }
        return;
    }
    const float* src = (yy == 0) ? a : (yy == 1) ? b : c;
    ushort_t* d = dst + (size_t)yy * ((size_t)n4 * 4);
    const float4 v = ((const float4*)src)[i];
    ushort4 o;
    o.x = f2bf(v.x); o.y = f2bf(v.y); o.z = f2bf(v.z); o.w = f2bf(v.w);
    ((ushort4*)d)[i] = o;
}

// ---------------- fused projection GEMM (Q/K/V via blockIdx.z) ----------------
__global__ __launch_bounds__(256) void gemm_proj(const ushort_t* __restrict__ Xall,
                                                 const ushort_t* __restrict__ Wall,
                                                 const float* __restrict__ qmas,
                                                 const float* __restrict__ kmas,
                                                 ushort_t* __restrict__ Qh,
                                                 ushort_t* __restrict__ Kh,
                                                 ushort_t* __restrict__ Vt) {
    __shared__ ushort_t As[128 * 32];
    __shared__ ushort_t Bs[128 * 32];
    const int z = blockIdx.z;
    const ushort_t* X  = Xall + (size_t)z * MROWS * DMODEL;
    const ushort_t* Wb = Wall + (size_t)z * DMODEL * DMODEL;
    const float* rowmask = (z == 0) ? qmas : kmas;

    const int tid  = threadIdx.x;
    const int wave = tid >> 6;
    const int lane = tid & 63;
    const int l16  = lane & 15;
    const int quad = lane >> 4;
    const int wr   = wave >> 1;
    const int wc   = wave & 1;
    const int m0   = blockIdx.x * 128;
    const int n0   = blockIdx.y * 128;
    const int crow = lane >> 2;
    const int koff = (lane & 3) * 8;

    floatx4 acc[4][4];
#pragma unroll
    for (int t = 0; t < 4; ++t)
#pragma unroll
        for (int u = 0; u < 4; ++u) acc[t][u] = (floatx4){0.f, 0.f, 0.f, 0.f};

    for (int k0 = 0; k0 < DMODEL; k0 += 32) {
#pragma unroll
        for (int c2 = 0; c2 < 2; ++c2) {
            const int c = wave * 2 + c2;
            gld16(X  + (size_t)(m0 + c * 16 + crow) * DMODEL + k0 + koff, &As[c * 512]);
            gld16(Wb + (size_t)(n0 + c * 16 + crow) * DMODEL + k0 + koff, &Bs[c * 512]);
        }
        __syncthreads();
        short8 a[4], b[4];
#pragma unroll
        for (int t = 0; t < 4; ++t)
            a[t] = *(const short8*)&As[(wr * 64 + t * 16 + l16) * 32 + quad * 8];
#pragma unroll
        for (int u = 0; u < 4; ++u)
            b[u] = *(const short8*)&Bs[(wc * 64 + u * 16 + l16) * 32 + quad * 8];
#pragma unroll
        for (int t = 0; t < 4; ++t)
#pragma unroll
            for (int u = 0; u < 4; ++u) acc[t][u] = mfma_bf16(a[t], b[u], acc[t][u]);
        __syncthreads();
    }

    float rm[4][4];
#pragma unroll
    for (int t = 0; t < 4; ++t)
#pragma unroll
        for (int r = 0; r < 4; ++r)
            rm[t][r] = rowmask[m0 + wr * 64 + t * 16 + quad * 4 + r];
    if (z == 0) {
        // fold log2(e)/sqrt(dk) into Qh so attn uses exp2(S) directly
#pragma unroll
        for (int t = 0; t < 4; ++t)
#pragma unroll
            for (int r = 0; r < 4; ++r) rm[t][r] *= 0.18033688011112042f;
    }

    const int bb    = m0 >> 11;
    const int nbase = (m0 & (NSEQ - 1)) + wr * 64;
#pragma unroll
    for (int t = 0; t < 4; ++t) {
#pragma unroll
        for (int u = 0; u < 4; ++u) {
            const int d = n0 + wc * 64 + u * 16 + l16;
            const int h = d >> 6, cc = d & 63;
            if (z < 2) {
                ushort_t* dst = (z == 0) ? Qh : Kh;
#pragma unroll
                for (int r = 0; r < 4; ++r) {
                    const int n = nbase + t * 16 + quad * 4 + r;
                    dst[((size_t)(bb * NH + h) * NSEQ + n) * DKH + cc] =
                        f2bf(acc[t][u][r] * rm[t][r]);
                }
            } else {
                ushort4 pk;
                pk.x = f2bf(acc[t][u][0] * rm[t][0]);
                pk.y = f2bf(acc[t][u][1] * rm[t][1]);
                pk.z = f2bf(acc[t][u][2] * rm[t][2]);
                pk.w = f2bf(acc[t][u][3] * rm[t][3]);
                const int n = nbase + t * 16 + quad * 4;
                *(ushort4*)(Vt + ((size_t)(bb * NH + h) * DKH + cc) * NSEQ + n) = pk;
            }
        }
    }
}

// ---------------- output GEMM ----------------
__global__ __launch_bounds__(256) void gemm_out(const ushort_t* __restrict__ X,
                                                const ushort_t* __restrict__ Wb,
                                                const float* __restrict__ rowmask,
                                                float* __restrict__ dst) {
    __shared__ ushort_t As[128 * 32];
    __shared__ ushort_t Bs[128 * 32];
    const int tid  = threadIdx.x;
    const int wave = tid >> 6;
    const int lane = tid & 63;
    const int l16  = lane & 15;
    const int quad = lane >> 4;
    const int wr   = wave >> 1;
    const int wc   = wave & 1;
    const int m0   = blockIdx.x * 128;
    const int n0   = blockIdx.y * 128;
    const int crow = lane >> 2;
    const int koff = (lane & 3) * 8;

    floatx4 acc[4][4];
#pragma unroll
    for (int t = 0; t < 4; ++t)
#pragma unroll
        for (int u = 0; u < 4; ++u) acc[t][u] = (floatx4){0.f, 0.f, 0.f, 0.f};

    for (int k0 = 0; k0 < DMODEL; k0 += 32) {
#pragma unroll
        for (int c2 = 0; c2 < 2; ++c2) {
            const int c = wave * 2 + c2;
            gld16(X  + (size_t)(m0 + c * 16 + crow) * DMODEL + k0 + koff, &As[c * 512]);
            gld16(Wb + (size_t)(n0 + c * 16 + crow) * DMODEL + k0 + koff, &Bs[c * 512]);
        }
        __syncthreads();
        short8 a[4], b[4];
#pragma unroll
        for (int t = 0; t < 4; ++t)
            a[t] = *(const short8*)&As[(wr * 64 + t * 16 + l16) * 32 + quad * 8];
#pragma unroll
        for (int u = 0; u < 4; ++u)
            b[u] = *(const short8*)&Bs[(wc * 64 + u * 16 + l16) * 32 + quad * 8];
#pragma unroll
        for (int t = 0; t < 4; ++t)
#pragma unroll
            for (int u = 0; u < 4; ++u) acc[t][u] = mfma_bf16(a[t], b[u], acc[t][u]);
        __syncthreads();
    }

#pragma unroll
    for (int t = 0; t < 4; ++t) {
#pragma unroll
        for (int r = 0; r < 4; ++r) {
            const int m = m0 + wr * 64 + t * 16 + quad * 4 + r;
            const float rm = rowmask[m];
#pragma unroll
            for (int u = 0; u < 4; ++u) {
                const int d = n0 + wc * 64 + u * 16 + l16;
                dst[(size_t)m * DMODEL + d] = acc[t][u][r] * rm;
            }
        }
    }
}

// ---------------- flash attention: 128-q blocks, 2 q-groups/wave, LDS 128-key tiles ----------------
// Qh (pre-scaled by log2e/8), Kh: [b][h][n][64] bf16;  Vt: [b][h][c][n] bf16;
// Mb: bit-packed att_mas (in d_out, overwritten later by gemm_out); kmas fp32.
// S computed TRANSPOSED (mfma(K,Q)): lane (l16,quad) reg r holds S[key][q=l16].
// Each wave owns 32 q-rows (2 groups of 16): every Ks fragment feeds 4 MFMAs and
// every Vs fragment feeds 2 MFMAs -> per-q LDS traffic ~cut in half (the kernel
// is LDS-pipe-bound: ~80% of cycles were DS issue + conflicts at 16 q/wave).
__global__ __launch_bounds__(256) void attn_kernel(const ushort_t* __restrict__ Qh,
                                                   const ushort_t* __restrict__ Kh,
                                                   const ushort_t* __restrict__ Vt,
                                                   const unsigned int* __restrict__ Mb,
                                                   const float* __restrict__ kmas,
                                                   ushort_t* __restrict__ y) {
    __shared__ __align__(16) ushort_t Ks[128 * 72];      // 18432 B
    __shared__ __align__(16) ushort_t Vs[64 * 136];      // 17408 B
    __shared__ __align__(16) ushort_t Ps[8][16 * 136];   // 34816 B (total 70656)

    const int tid  = threadIdx.x;
    const int wave = tid >> 6;
    const int lane = tid & 63;
    const int l16  = lane & 15;
    const int quad = lane >> 4;
    const int h    = blockIdx.y;
    const int b    = blockIdx.z;
    const int qw   = blockIdx.x * 128 + wave * 32;   // this wave's 32 q-rows

    ushort_t* Ps0 = Ps[wave * 2];
    ushort_t* Ps1 = Ps[wave * 2 + 1];

    const ushort_t* Kb = Kh + (size_t)(b * NH + h) * NSEQ * DKH;
    const ushort_t* Vb = Vt + (size_t)(b * NH + h) * DKH * NSEQ;
    // per-lane mask rows: q = qw + l16 (group 0) and qw + 16 + l16 (group 1)
    const uint4* Mv0 = (const uint4*)(Mb + ((size_t)(b * NSEQ + qw) + l16) * NW32);
    const uint4* Mv1 = (const uint4*)(Mb + ((size_t)(b * NSEQ + qw) + 16 + l16) * NW32);

    const ushort_t* Qp0 = Qh + ((size_t)((b * NH + h) * NSEQ) + qw + l16) * DKH + quad * 8;
    const ushort_t* Qp1 = Qp0 + 16 * DKH;
    const short8 qf0a = *(const short8*)Qp0;
    const short8 qf0b = *(const short8*)(Qp0 + 32);
    const short8 qf1a = *(const short8*)Qp1;
    const short8 qf1b = *(const short8*)(Qp1 + 32);

    float lp0 = 0.f, lp1 = 0.f;   // P row-sums for q-rows (qw+l16), (qw+16+l16)
    floatx4 accA[4], accB[4];
#pragma unroll
    for (int ct = 0; ct < 4; ++ct) {
        accA[ct] = (floatx4){0.f, 0.f, 0.f, 0.f};
        accB[ct] = (floatx4){0.f, 0.f, 0.f, 0.f};
    }

    for (int kt = 0; kt < NSEQ / 128; ++kt) {
        const int k0 = kt * 128;

        // ---- gather staging data into VGPRs (coalesced 16B/lane) ----
        short8 kv[4], vv[4];
#pragma unroll
        for (int i = 0; i < 4; ++i) {
            const int c = tid + i * 256;
            kv[i] = *(const short8*)(Kb + (size_t)(k0 + (c >> 3)) * DKH + (c & 7) * 8);
        }
#pragma unroll
        for (int i = 0; i < 4; ++i) {
            const int c = tid + i * 256;
            vv[i] = *(const short8*)(Vb + (size_t)(c >> 4) * NSEQ + k0 + (c & 15) * 8);
        }
        const uint4 mw0 = Mv0[kt];
        const uint4 mw1 = Mv1[kt];

        __syncthreads();   // (a) previous tile's LDS reads complete
#pragma unroll
        for (int i = 0; i < 4; ++i) {
            const int c = tid + i * 256;
            *(short8*)&Ks[(c >> 3) * 72 + (c & 7) * 8] = kv[i];
        }
#pragma unroll
        for (int i = 0; i < 4; ++i) {
            const int c = tid + i * 256;
            *(short8*)&Vs[(c >> 4) * 136 + (c & 15) * 8] = vv[i];
        }
        __syncthreads();   // (b) tile staged

        // ---- fused S^T + softmax, K fragment read once -> both q-groups ----
        const unsigned int wsh0[4] = {mw0.x >> (quad * 4), mw0.y >> (quad * 4),
                                      mw0.z >> (quad * 4), mw0.w >> (quad * 4)};
        const unsigned int wsh1[4] = {mw1.x >> (quad * 4), mw1.y >> (quad * 4),
                                      mw1.z >> (quad * 4), mw1.w >> (quad * 4)};
#pragma unroll
        for (int fr = 0; fr < 8; ++fr) {
            const short8 ka = *(const short8*)&Ks[(fr * 16 + l16) * 72 + quad * 8];
            const short8 kb = *(const short8*)&Ks[(fr * 16 + l16) * 72 + 32 + quad * 8];
            floatx4 s0 = {0.f, 0.f, 0.f, 0.f};
            s0 = mfma_bf16(ka, qf0a, s0);
            s0 = mfma_bf16(kb, qf0b, s0);
            floatx4 s1 = {0.f, 0.f, 0.f, 0.f};
            s1 = mfma_bf16(ka, qf1a, s1);
            s1 = mfma_bf16(kb, qf1b, s1);

            float p0[4], p1[4];
#pragma unroll
            for (int r = 0; r < 4; ++r) {
                const int bitp = ((fr & 1) << 4) + r;
                const unsigned int m0m =
                    (unsigned int)__builtin_amdgcn_sbfe((int)wsh0[fr >> 1], bitp, 1);
                const unsigned int m1m =
                    (unsigned int)__builtin_amdgcn_sbfe((int)wsh1[fr >> 1], bitp, 1);
                const unsigned int pb0 =
                    __builtin_bit_cast(unsigned int, exp2f(s0[r])) & m0m;
                const unsigned int pb1 =
                    __builtin_bit_cast(unsigned int, exp2f(s1[r])) & m1m;
                p0[r] = __builtin_bit_cast(float, pb0);
                p1[r] = __builtin_bit_cast(float, pb1);
                lp0 += p0[r];
                lp1 += p1[r];
            }
            uint2 pk0, pk1;
            pk0.x = cvt_pk_bf16(p0[0], p0[1]);
            pk0.y = cvt_pk_bf16(p0[2], p0[3]);
            pk1.x = cvt_pk_bf16(p1[0], p1[1]);
            pk1.y = cvt_pk_bf16(p1[2], p1[3]);
            *(uint2*)&Ps0[l16 * 136 + fr * 16 + quad * 4] = pk0;
            *(uint2*)&Ps1[l16 * 136 + fr * 16 + quad * 4] = pk1;
        }

        __builtin_amdgcn_wave_barrier();  // LDS W->R order (wave-local, in-order DS pipe)
        short8 pf0[4], pf1[4];
#pragma unroll
        for (int kf = 0; kf < 4; ++kf) {
            pf0[kf] = *(const short8*)&Ps0[l16 * 136 + kf * 32 + quad * 8];
            pf1[kf] = *(const short8*)&Ps1[l16 * 136 + kf * 32 + quad * 8];
        }
        __builtin_amdgcn_wave_barrier();

        // ---- O += P.V : each V fragment read once -> both q-groups ----
#pragma unroll
        for (int ct = 0; ct < 4; ++ct) {
#pragma unroll
            for (int kf = 0; kf < 4; ++kf) {
                const short8 vb = *(const short8*)&Vs[(ct * 16 + l16) * 136 + kf * 32 + quad * 8];
                accA[ct] = mfma_bf16(pf0[kf], vb, accA[ct]);
                accB[ct] = mfma_bf16(pf1[kf], vb, accB[ct]);
            }
        }
    }

    // ---- epilogue: per group, reduce l across quads, normalize, post-mask, store ----
    float lf0 = lp0, lf1 = lp1;
    lf0 += __shfl_xor(lf0, 16);
    lf0 += __shfl_xor(lf0, 32);   // lane holds full l for q-row (qw + l16)
    lf1 += __shfl_xor(lf1, 16);
    lf1 += __shfl_xor(lf1, 32);   // lane holds full l for q-row (qw + 16 + l16)
#pragma unroll
    for (int r = 0; r < 4; ++r) {
        const int q0 = qw + quad * 4 + r;
        const int q1 = q0 + 16;
        const float l0 = __shfl(lf0, quad * 4 + r);
        const float l1 = __shfl(lf1, quad * 4 + r);
        const float sc0 = kmas[b * NSEQ + q0] / l0;
        const float sc1 = kmas[b * NSEQ + q1] / l1;
#pragma unroll
        for (int ct = 0; ct < 4; ++ct) {
            y[(size_t)(b * NSEQ + q0) * DMODEL + h * DKH + ct * 16 + l16] =
                f2bf(accA[ct][r] * sc0);
            y[(size_t)(b * NSEQ + q1) * DMODEL + h * DKH + ct * 16 + l16] =
                f2bf(accB[ct][r] * sc1);
        }
    }
}

extern "C" void kernel_launch(void* const* d_in, const int* in_sizes, int n_in,
                              void* d_out, int out_size, void* d_ws, size_t ws_size,
                              hipStream_t stream) {
    (void)in_sizes; (void)n_in; (void)out_size; (void)ws_size;
    const float* Q  = (const float*)d_in[0];
    const float* K  = (const float*)d_in[1];
    const float* V  = (const float*)d_in[2];
    const float* qm = (const float*)d_in[3];
    const float* km = (const float*)d_in[4];
    const float* am = (const float*)d_in[5];
    const float* WQ = (const float*)d_in[6];
    const float* WK = (const float*)d_in[7];
    const float* WV = (const float*)d_in[8];
    const float* WO = (const float*)d_in[9];

    const size_t XN = (size_t)MROWS * DMODEL;        // 4,194,304
    const size_t WN = (size_t)DMODEL * DMODEL;       // 262,144
    ushort_t* Xbf = (ushort_t*)d_ws;                 // Q,K,V bf16: 3*XN
    ushort_t* Wbf = Xbf + 3 * XN;                    // WQ,WK,WV,WO bf16: 4*WN
    ushort_t* WOb = Wbf + 3 * WN;
    ushort_t* Qh  = Wbf + 4 * WN;
    ushort_t* Kh  = Qh + XN;
    ushort_t* Vt  = Kh + XN;
    ushort_t* y   = Vt + XN;
    // packed mask lives in d_out (2 MB of 16 MB); gemm_out fully overwrites d_out afterwards
    unsigned int* Mbits = (unsigned int*)d_out;
    float* out = (float*)d_out;

    hipLaunchKernelGGL(cvt_all, dim3(4096, 5), dim3(256), 0, stream,
                       Q, K, V, WQ, WK, WV, WO, am, Xbf, Wbf, Mbits, (int)(XN / 4));

    hipLaunchKernelGGL(gemm_proj, dim3(MROWS / 128, DMODEL / 128, 3), dim3(256), 0, stream,
                       Xbf, Wbf, qm, km, Qh, Kh, Vt);

    hipLaunchKernelGGL(attn_kernel, dim3(NSEQ / 128, NH, BS_), dim3(256), 0, stream,
                       Qh, Kh, Vt, Mbits, km, y);

    hipLaunchKernelGGL(gemm_out, dim3(MROWS / 128, DMODEL / 128), dim3(256), 0, stream,
                       y, WOb, km, out);
}

// Round 8
// 267.278 us; speedup vs baseline: 1.3286x; 1.0547x over previous
//
#include <hip/hip_runtime.h>

// MultiHeadAttention: BS=4, N=2048, D=512, H=8, DK=64. fp32 in/out, bf16 MFMA compute.
// Round 13: l (softmax denominator) computed on the MFMA pipe via mfma(P, ones):
// removes the 64-deep dependent lpart add chain per group per tile (fp adds can't
// be reassociated) and the 12-shuffle epilogue reduction; D-layout lands l at
// exactly the epilogue indexing (q = quad*4+r, uniform over l16). exp2 forced to
// raw v_exp_f32. Structure otherwise = R12 (2 q-groups/wave, LDS-staged tiles).

#define BS_    4
#define NSEQ   2048
#define DMODEL 512
#define NH     8
#define DKH    64
#define MROWS  (BS_ * NSEQ)   // 8192
#define NW32   (NSEQ / 32)    // 64 mask words per row
#define NWORDS (BS_ * NSEQ * NSEQ / 32)  // 524288 packed mask words

typedef unsigned short ushort_t;
typedef __attribute__((ext_vector_type(8))) short short8;   // 8 bf16 (4 VGPRs)
typedef __attribute__((ext_vector_type(4))) float floatx4;  // 4 fp32 acc

__device__ __forceinline__ ushort_t f2bf(float f) {
    unsigned int x = __builtin_bit_cast(unsigned int, f);
    unsigned int lsb = (x >> 16) & 1u;
    x += 0x7fffu + lsb;          // round-to-nearest-even
    return (ushort_t)(x >> 16);
}
__device__ __forceinline__ floatx4 mfma_bf16(short8 a, short8 b, floatx4 c) {
    return __builtin_amdgcn_mfma_f32_16x16x32_bf16(a, b, c, 0, 0, 0);
}
__device__ __forceinline__ void gld16(const ushort_t* g, ushort_t* l) {
    __builtin_amdgcn_global_load_lds(
        (const __attribute__((address_space(1))) unsigned int*)g,
        (__attribute__((address_space(3))) unsigned int*)l, 16, 0, 0);
}
__device__ __forceinline__ unsigned int cvt_pk_bf16(float lo, float hi) {
    unsigned int r;
    asm("v_cvt_pk_bf16_f32 %0, %1, %2" : "=v"(r) : "v"(lo), "v"(hi));
    return r;
}
__device__ __forceinline__ float fexp2(float x) {
#if __has_builtin(__builtin_amdgcn_exp2f)
    return __builtin_amdgcn_exp2f(x);   // raw v_exp_f32
#else
    return exp2f(x);
#endif
}

// ---------------- fp32 -> bf16 converts + weights + att_mas bit-pack ----------------
// grid (4096, 5): y=0..2 QKV slices; y=3 weights (WQ,WK,WV,WO contiguous); y=4 mask
__global__ __launch_bounds__(256) void cvt_all(const float* __restrict__ a,
                                               const float* __restrict__ b,
                                               const float* __restrict__ c,
                                               const float* __restrict__ wq,
                                               const float* __restrict__ wk,
                                               const float* __restrict__ wv,
                                               const float* __restrict__ wo,
                                               const float* __restrict__ am,
                                               ushort_t* __restrict__ dst,
                                               ushort_t* __restrict__ wdst,
                                               unsigned int* __restrict__ mb, int n4) {
    const int i = blockIdx.x * blockDim.x + threadIdx.x;
    const int yy = blockIdx.y;
    if (yy == 4) {
        // bit-pack att_mas: word t covers att[32t..32t+31]; bit j = (att != 0)
        if (i < NWORDS) {
            const float4* src = (const float4*)am + (size_t)i * 8;
            unsigned int m = 0;
#pragma unroll
            for (int j = 0; j < 8; ++j) {
                const float4 v = src[j];
                m |= (v.x != 0.f ? 1u : 0u) << (4 * j);
                m |= (v.y != 0.f ? 1u : 0u) << (4 * j + 1);
                m |= (v.z != 0.f ? 1u : 0u) << (4 * j + 2);
                m |= (v.w != 0.f ? 1u : 0u) << (4 * j + 3);
            }
            mb[i] = m;
        }
        return;
    }
    if (yy == 3) {
        const int wn4 = DMODEL * DMODEL / 4;          // 65536 float4 per weight
        if (i < 4 * wn4) {
            const int w = i >> 16;
            const float* src = (w == 0) ? wq : (w == 1) ? wk : (w == 2) ? wv : wo;
            const float4 v = ((const float4*)src)[i & (wn4 - 1)];
            ushort4 o;
            o.x = f2bf(v.x); o.y = f2bf(v.y); o.z = f2bf(v.z); o.w = f2bf(v.w);
            ((ushort4*)wdst)[i] = o;
        }
        return;
    }
    const float* src = (yy == 0) ? a : (yy == 1) ? b : c;
    ushort_t* d = dst + (size_t)yy * ((size_t)n4 * 4);
    const float4 v = ((const float4*)src)[i];
    ushort4 o;
    o.x = f2bf(v.x); o.y = f2bf(v.y); o.z = f2bf(v.z); o.w = f2bf(v.w);
    ((ushort4*)d)[i] = o;
}

// ---------------- fused projection GEMM (Q/K/V via blockIdx.z) ----------------
__global__ __launch_bounds__(256) void gemm_proj(const ushort_t* __restrict__ Xall,
                                                 const ushort_t* __restrict__ Wall,
                                                 const float* __restrict__ qmas,
                                                 const float* __restrict__ kmas,
                                                 ushort_t* __restrict__ Qh,
                                                 ushort_t* __restrict__ Kh,
                                                 ushort_t* __restrict__ Vt) {
    __shared__ ushort_t As[128 * 32];
    __shared__ ushort_t Bs[128 * 32];
    const int z = blockIdx.z;
    const ushort_t* X  = Xall + (size_t)z * MROWS * DMODEL;
    const ushort_t* Wb = Wall + (size_t)z * DMODEL * DMODEL;
    const float* rowmask = (z == 0) ? qmas : kmas;

    const int tid  = threadIdx.x;
    const int wave = tid >> 6;
    const int lane = tid & 63;
    const int l16  = lane & 15;
    const int quad = lane >> 4;
    const int wr   = wave >> 1;
    const int wc   = wave & 1;
    const int m0   = blockIdx.x * 128;
    const int n0   = blockIdx.y * 128;
    const int crow = lane >> 2;
    const int koff = (lane & 3) * 8;

    floatx4 acc[4][4];
#pragma unroll
    for (int t = 0; t < 4; ++t)
#pragma unroll
        for (int u = 0; u < 4; ++u) acc[t][u] = (floatx4){0.f, 0.f, 0.f, 0.f};

    for (int k0 = 0; k0 < DMODEL; k0 += 32) {
#pragma unroll
        for (int c2 = 0; c2 < 2; ++c2) {
            const int c = wave * 2 + c2;
            gld16(X  + (size_t)(m0 + c * 16 + crow) * DMODEL + k0 + koff, &As[c * 512]);
            gld16(Wb + (size_t)(n0 + c * 16 + crow) * DMODEL + k0 + koff, &Bs[c * 512]);
        }
        __syncthreads();
        short8 a[4], b[4];
#pragma unroll
        for (int t = 0; t < 4; ++t)
            a[t] = *(const short8*)&As[(wr * 64 + t * 16 + l16) * 32 + quad * 8];
#pragma unroll
        for (int u = 0; u < 4; ++u)
            b[u] = *(const short8*)&Bs[(wc * 64 + u * 16 + l16) * 32 + quad * 8];
#pragma unroll
        for (int t = 0; t < 4; ++t)
#pragma unroll
            for (int u = 0; u < 4; ++u) acc[t][u] = mfma_bf16(a[t], b[u], acc[t][u]);
        __syncthreads();
    }

    float rm[4][4];
#pragma unroll
    for (int t = 0; t < 4; ++t)
#pragma unroll
        for (int r = 0; r < 4; ++r)
            rm[t][r] = rowmask[m0 + wr * 64 + t * 16 + quad * 4 + r];
    if (z == 0) {
        // fold log2(e)/sqrt(dk) into Qh so attn uses exp2(S) directly
#pragma unroll
        for (int t = 0; t < 4; ++t)
#pragma unroll
            for (int r = 0; r < 4; ++r) rm[t][r] *= 0.18033688011112042f;
    }

    const int bb    = m0 >> 11;
    const int nbase = (m0 & (NSEQ - 1)) + wr * 64;
#pragma unroll
    for (int t = 0; t < 4; ++t) {
#pragma unroll
        for (int u = 0; u < 4; ++u) {
            const int d = n0 + wc * 64 + u * 16 + l16;
            const int h = d >> 6, cc = d & 63;
            if (z < 2) {
                ushort_t* dst = (z == 0) ? Qh : Kh;
#pragma unroll
                for (int r = 0; r < 4; ++r) {
                    const int n = nbase + t * 16 + quad * 4 + r;
                    dst[((size_t)(bb * NH + h) * NSEQ + n) * DKH + cc] =
                        f2bf(acc[t][u][r] * rm[t][r]);
                }
            } else {
                ushort4 pk;
                pk.x = f2bf(acc[t][u][0] * rm[t][0]);
                pk.y = f2bf(acc[t][u][1] * rm[t][1]);
                pk.z = f2bf(acc[t][u][2] * rm[t][2]);
                pk.w = f2bf(acc[t][u][3] * rm[t][3]);
                const int n = nbase + t * 16 + quad * 4;
                *(ushort4*)(Vt + ((size_t)(bb * NH + h) * DKH + cc) * NSEQ + n) = pk;
            }
        }
    }
}

// ---------------- output GEMM ----------------
__global__ __launch_bounds__(256) void gemm_out(const ushort_t* __restrict__ X,
                                                const ushort_t* __restrict__ Wb,
                                                const float* __restrict__ rowmask,
                                                float* __restrict__ dst) {
    __shared__ ushort_t As[128 * 32];
    __shared__ ushort_t Bs[128 * 32];
    const int tid  = threadIdx.x;
    const int wave = tid >> 6;
    const int lane = tid & 63;
    const int l16  = lane & 15;
    const int quad = lane >> 4;
    const int wr   = wave >> 1;
    const int wc   = wave & 1;
    const int m0   = blockIdx.x * 128;
    const int n0   = blockIdx.y * 128;
    const int crow = lane >> 2;
    const int koff = (lane & 3) * 8;

    floatx4 acc[4][4];
#pragma unroll
    for (int t = 0; t < 4; ++t)
#pragma unroll
        for (int u = 0; u < 4; ++u) acc[t][u] = (floatx4){0.f, 0.f, 0.f, 0.f};

    for (int k0 = 0; k0 < DMODEL; k0 += 32) {
#pragma unroll
        for (int c2 = 0; c2 < 2; ++c2) {
            const int c = wave * 2 + c2;
            gld16(X  + (size_t)(m0 + c * 16 + crow) * DMODEL + k0 + koff, &As[c * 512]);
            gld16(Wb + (size_t)(n0 + c * 16 + crow) * DMODEL + k0 + koff, &Bs[c * 512]);
        }
        __syncthreads();
        short8 a[4], b[4];
#pragma unroll
        for (int t = 0; t < 4; ++t)
            a[t] = *(const short8*)&As[(wr * 64 + t * 16 + l16) * 32 + quad * 8];
#pragma unroll
        for (int u = 0; u < 4; ++u)
            b[u] = *(const short8*)&Bs[(wc * 64 + u * 16 + l16) * 32 + quad * 8];
#pragma unroll
        for (int t = 0; t < 4; ++t)
#pragma unroll
            for (int u = 0; u < 4; ++u) acc[t][u] = mfma_bf16(a[t], b[u], acc[t][u]);
        __syncthreads();
    }

#pragma unroll
    for (int t = 0; t < 4; ++t) {
#pragma unroll
        for (int r = 0; r < 4; ++r) {
            const int m = m0 + wr * 64 + t * 16 + quad * 4 + r;
            const float rm = rowmask[m];
#pragma unroll
            for (int u = 0; u < 4; ++u) {
                const int d = n0 + wc * 64 + u * 16 + l16;
                dst[(size_t)m * DMODEL + d] = acc[t][u][r] * rm;
            }
        }
    }
}

// ---------------- flash attention: 128-q blocks, 2 q-groups/wave, LDS 128-key tiles ----------------
// Qh (pre-scaled by log2e/8), Kh: [b][h][n][64] bf16;  Vt: [b][h][c][n] bf16;
// Mb: bit-packed att_mas (in d_out, overwritten later by gemm_out); kmas fp32.
// S computed TRANSPOSED (mfma(K,Q)): lane (l16,quad) reg r holds S[key][q=l16].
// Each wave owns 32 q-rows (2 groups of 16); K/V fragments read once feed both.
// l computed via mfma(P, ones): D row = quad*4+r = epilogue q indexing, no shuffles,
// no serial f32 add chain.
__global__ __launch_bounds__(256) void attn_kernel(const ushort_t* __restrict__ Qh,
                                                   const ushort_t* __restrict__ Kh,
                                                   const ushort_t* __restrict__ Vt,
                                                   const unsigned int* __restrict__ Mb,
                                                   const float* __restrict__ kmas,
                                                   ushort_t* __restrict__ y) {
    __shared__ __align__(16) ushort_t Ks[128 * 72];      // 18432 B
    __shared__ __align__(16) ushort_t Vs[64 * 136];      // 17408 B
    __shared__ __align__(16) ushort_t Ps[8][16 * 136];   // 34816 B (total 70656)

    const int tid  = threadIdx.x;
    const int wave = tid >> 6;
    const int lane = tid & 63;
    const int l16  = lane & 15;
    const int quad = lane >> 4;
    const int h    = blockIdx.y;
    const int b    = blockIdx.z;
    const int qw   = blockIdx.x * 128 + wave * 32;   // this wave's 32 q-rows

    ushort_t* Ps0 = Ps[wave * 2];
    ushort_t* Ps1 = Ps[wave * 2 + 1];

    const ushort_t* Kb = Kh + (size_t)(b * NH + h) * NSEQ * DKH;
    const ushort_t* Vb = Vt + (size_t)(b * NH + h) * DKH * NSEQ;
    // per-lane mask rows: q = qw + l16 (group 0) and qw + 16 + l16 (group 1)
    const uint4* Mv0 = (const uint4*)(Mb + ((size_t)(b * NSEQ + qw) + l16) * NW32);
    const uint4* Mv1 = (const uint4*)(Mb + ((size_t)(b * NSEQ + qw) + 16 + l16) * NW32);

    const ushort_t* Qp0 = Qh + ((size_t)((b * NH + h) * NSEQ) + qw + l16) * DKH + quad * 8;
    const ushort_t* Qp1 = Qp0 + 16 * DKH;
    const short8 qf0a = *(const short8*)Qp0;
    const short8 qf0b = *(const short8*)(Qp0 + 32);
    const short8 qf1a = *(const short8*)Qp1;
    const short8 qf1b = *(const short8*)(Qp1 + 32);

    // all-ones bf16 B-operand for row-sum MFMA (bf16 1.0 = 0x3F80)
    const short8 ones = {(short)0x3F80, (short)0x3F80, (short)0x3F80, (short)0x3F80,
                         (short)0x3F80, (short)0x3F80, (short)0x3F80, (short)0x3F80};

    floatx4 accA[4], accB[4];
    floatx4 accL0 = (floatx4){0.f, 0.f, 0.f, 0.f};   // row-sums l, group 0
    floatx4 accL1 = (floatx4){0.f, 0.f, 0.f, 0.f};   // row-sums l, group 1
#pragma unroll
    for (int ct = 0; ct < 4; ++ct) {
        accA[ct] = (floatx4){0.f, 0.f, 0.f, 0.f};
        accB[ct] = (floatx4){0.f, 0.f, 0.f, 0.f};
    }

    for (int kt = 0; kt < NSEQ / 128; ++kt) {
        const int k0 = kt * 128;

        // ---- gather staging data into VGPRs (coalesced 16B/lane) ----
        short8 kv[4], vv[4];
#pragma unroll
        for (int i = 0; i < 4; ++i) {
            const int c = tid + i * 256;
            kv[i] = *(const short8*)(Kb + (size_t)(k0 + (c >> 3)) * DKH + (c & 7) * 8);
        }
#pragma unroll
        for (int i = 0; i < 4; ++i) {
            const int c = tid + i * 256;
            vv[i] = *(const short8*)(Vb + (size_t)(c >> 4) * NSEQ + k0 + (c & 15) * 8);
        }
        const uint4 mw0 = Mv0[kt];
        const uint4 mw1 = Mv1[kt];

        __syncthreads();   // (a) previous tile's LDS reads complete
#pragma unroll
        for (int i = 0; i < 4; ++i) {
            const int c = tid + i * 256;
            *(short8*)&Ks[(c >> 3) * 72 + (c & 7) * 8] = kv[i];
        }
#pragma unroll
        for (int i = 0; i < 4; ++i) {
            const int c = tid + i * 256;
            *(short8*)&Vs[(c >> 4) * 136 + (c & 15) * 8] = vv[i];
        }
        __syncthreads();   // (b) tile staged

        // ---- fused S^T + softmax, K fragment read once -> both q-groups ----
        const unsigned int wsh0[4] = {mw0.x >> (quad * 4), mw0.y >> (quad * 4),
                                      mw0.z >> (quad * 4), mw0.w >> (quad * 4)};
        const unsigned int wsh1[4] = {mw1.x >> (quad * 4), mw1.y >> (quad * 4),
                                      mw1.z >> (quad * 4), mw1.w >> (quad * 4)};
#pragma unroll
        for (int fr = 0; fr < 8; ++fr) {
            const short8 ka = *(const short8*)&Ks[(fr * 16 + l16) * 72 + quad * 8];
            const short8 kb = *(const short8*)&Ks[(fr * 16 + l16) * 72 + 32 + quad * 8];
            floatx4 s0 = {0.f, 0.f, 0.f, 0.f};
            s0 = mfma_bf16(ka, qf0a, s0);
            s0 = mfma_bf16(kb, qf0b, s0);
            floatx4 s1 = {0.f, 0.f, 0.f, 0.f};
            s1 = mfma_bf16(ka, qf1a, s1);
            s1 = mfma_bf16(kb, qf1b, s1);

            float p0[4], p1[4];
#pragma unroll
            for (int r = 0; r < 4; ++r) {
                const int bitp = ((fr & 1) << 4) + r;
                const unsigned int m0m =
                    (unsigned int)__builtin_amdgcn_sbfe((int)wsh0[fr >> 1], bitp, 1);
                const unsigned int m1m =
                    (unsigned int)__builtin_amdgcn_sbfe((int)wsh1[fr >> 1], bitp, 1);
                const unsigned int pb0 =
                    __builtin_bit_cast(unsigned int, fexp2(s0[r])) & m0m;
                const unsigned int pb1 =
                    __builtin_bit_cast(unsigned int, fexp2(s1[r])) & m1m;
                p0[r] = __builtin_bit_cast(float, pb0);
                p1[r] = __builtin_bit_cast(float, pb1);
            }
            uint2 pk0, pk1;
            pk0.x = cvt_pk_bf16(p0[0], p0[1]);
            pk0.y = cvt_pk_bf16(p0[2], p0[3]);
            pk1.x = cvt_pk_bf16(p1[0], p1[1]);
            pk1.y = cvt_pk_bf16(p1[2], p1[3]);
            *(uint2*)&Ps0[l16 * 136 + fr * 16 + quad * 4] = pk0;
            *(uint2*)&Ps1[l16 * 136 + fr * 16 + quad * 4] = pk1;
        }

        __builtin_amdgcn_wave_barrier();  // LDS W->R order (wave-local, in-order DS pipe)
        short8 pf0[4], pf1[4];
#pragma unroll
        for (int kf = 0; kf < 4; ++kf) {
            pf0[kf] = *(const short8*)&Ps0[l16 * 136 + kf * 32 + quad * 8];
            pf1[kf] = *(const short8*)&Ps1[l16 * 136 + kf * 32 + quad * 8];
        }
        __builtin_amdgcn_wave_barrier();

        // ---- l += P.1 on the MFMA pipe (replaces serial f32 add chains) ----
#pragma unroll
        for (int kf = 0; kf < 4; ++kf) {
            accL0 = mfma_bf16(pf0[kf], ones, accL0);
            accL1 = mfma_bf16(pf1[kf], ones, accL1);
        }

        // ---- O += P.V : each V fragment read once -> both q-groups ----
#pragma unroll
        for (int ct = 0; ct < 4; ++ct) {
#pragma unroll
            for (int kf = 0; kf < 4; ++kf) {
                const short8 vb = *(const short8*)&Vs[(ct * 16 + l16) * 136 + kf * 32 + quad * 8];
                accA[ct] = mfma_bf16(pf0[kf], vb, accA[ct]);
                accB[ct] = mfma_bf16(pf1[kf], vb, accB[ct]);
            }
        }
    }

    // ---- epilogue: l is in accL at exactly (q = qw + quad*4 + r); no shuffles ----
#pragma unroll
    for (int r = 0; r < 4; ++r) {
        const int q0 = qw + quad * 4 + r;
        const int q1 = q0 + 16;
        const float sc0 = kmas[b * NSEQ + q0] / accL0[r];
        const float sc1 = kmas[b * NSEQ + q1] / accL1[r];
#pragma unroll
        for (int ct = 0; ct < 4; ++ct) {
            y[(size_t)(b * NSEQ + q0) * DMODEL + h * DKH + ct * 16 + l16] =
                f2bf(accA[ct][r] * sc0);
            y[(size_t)(b * NSEQ + q1) * DMODEL + h * DKH + ct * 16 + l16] =
                f2bf(accB[ct][r] * sc1);
        }
    }
}

extern "C" void kernel_launch(void* const* d_in, const int* in_sizes, int n_in,
                              void* d_out, int out_size, void* d_ws, size_t ws_size,
                              hipStream_t stream) {
    (void)in_sizes; (void)n_in; (void)out_size; (void)ws_size;
    const float* Q  = (const float*)d_in[0];
    const float* K  = (const float*)d_in[1];
    const float* V  = (const float*)d_in[2];
    const float* qm = (const float*)d_in[3];
    const float* km = (const float*)d_in[4];
    const float* am = (const float*)d_in[5];
    const float* WQ = (const float*)d_in[6];
    const float* WK = (const float*)d_in[7];
    const float* WV = (const float*)d_in[8];
    const float* WO = (const float*)d_in[9];

    const size_t XN = (size_t)MROWS * DMODEL;        // 4,194,304
    const size_t WN = (size_t)DMODEL * DMODEL;       // 262,144
    ushort_t* Xbf = (ushort_t*)d_ws;                 // Q,K,V bf16: 3*XN
    ushort_t* Wbf = Xbf + 3 * XN;                    // WQ,WK,WV,WO bf16: 4*WN
    ushort_t* WOb = Wbf + 3 * WN;
    ushort_t* Qh  = Wbf + 4 * WN;
    ushort_t* Kh  = Qh + XN;
    ushort_t* Vt  = Kh + XN;
    ushort_t* y   = Vt + XN;
    // packed mask lives in d_out (2 MB of 16 MB); gemm_out fully overwrites d_out afterwards
    unsigned int* Mbits = (unsigned int*)d_out;
    float* out = (float*)d_out;

    hipLaunchKernelGGL(cvt_all, dim3(4096, 5), dim3(256), 0, stream,
                       Q, K, V, WQ, WK, WV, WO, am, Xbf, Wbf, Mbits, (int)(XN / 4));

    hipLaunchKernelGGL(gemm_proj, dim3(MROWS / 128, DMODEL / 128, 3), dim3(256), 0, stream,
                       Xbf, Wbf, qm, km, Qh, Kh, Vt);

    hipLaunchKernelGGL(attn_kernel, dim3(NSEQ / 128, NH, BS_), dim3(256), 0, stream,
                       Qh, Kh, Vt, Mbits, km, y);

    hipLaunchKernelGGL(gemm_out, dim3(MROWS / 128, DMODEL / 128), dim3(256), 0, stream,
                       y, WOb, km, out);
}

// Round 9
// 261.426 us; speedup vs baseline: 1.3583x; 1.0224x over previous
//
#include <hip/hip_runtime.h>

// MultiHeadAttention: BS=4, N=2048, D=512, H=8, DK=64. fp32 in/out, bf16 MFMA compute.
// Round 14: P transpose (S^T layout -> PV A-operand) moved off the LDS pipe:
// v_permlane32_swap + v_permlane16_swap (gfx950 VALU) redistribute cvt_pk'd P
// across quads in-register. Removes 16 b64 writes + 8 b128 reads + 2 wave_barriers
// per wave-tile and frees the 34.8KB Ps buffer (LDS 70656 -> 35840 B).
// Fused per-kf pipeline: S(2 frags) -> softmax -> permlane -> l-MFMA + PV.

#define BS_    4
#define NSEQ   2048
#define DMODEL 512
#define NH     8
#define DKH    64
#define MROWS  (BS_ * NSEQ)   // 8192
#define NW32   (NSEQ / 32)    // 64 mask words per row
#define NWORDS (BS_ * NSEQ * NSEQ / 32)  // 524288 packed mask words

typedef unsigned short ushort_t;
typedef __attribute__((ext_vector_type(8))) short short8;   // 8 bf16 (4 VGPRs)
typedef __attribute__((ext_vector_type(4))) float floatx4;  // 4 fp32 acc

__device__ __forceinline__ ushort_t f2bf(float f) {
    unsigned int x = __builtin_bit_cast(unsigned int, f);
    unsigned int lsb = (x >> 16) & 1u;
    x += 0x7fffu + lsb;          // round-to-nearest-even
    return (ushort_t)(x >> 16);
}
__device__ __forceinline__ floatx4 mfma_bf16(short8 a, short8 b, floatx4 c) {
    return __builtin_amdgcn_mfma_f32_16x16x32_bf16(a, b, c, 0, 0, 0);
}
__device__ __forceinline__ void gld16(const ushort_t* g, ushort_t* l) {
    __builtin_amdgcn_global_load_lds(
        (const __attribute__((address_space(1))) unsigned int*)g,
        (__attribute__((address_space(3))) unsigned int*)l, 16, 0, 0);
}
__device__ __forceinline__ unsigned int cvt_pk_bf16(float lo, float hi) {
    unsigned int r;
    asm("v_cvt_pk_bf16_f32 %0, %1, %2" : "=v"(r) : "v"(lo), "v"(hi));
    return r;
}
__device__ __forceinline__ float fexp2(float x) {
#if __has_builtin(__builtin_amdgcn_exp2f)
    return __builtin_amdgcn_exp2f(x);   // raw v_exp_f32
#else
    return exp2f(x);
#endif
}
// gfx950: swap a[32:63] <-> b[0:31]
__device__ __forceinline__ void permlane32_swap(unsigned& a, unsigned& b) {
    asm volatile("v_permlane32_swap_b32 %0, %1" : "+v"(a), "+v"(b));
}
// gfx950: swap a[16:31]<->b[0:15] and a[48:63]<->b[32:47]
__device__ __forceinline__ void permlane16_swap(unsigned& a, unsigned& b) {
    asm volatile("v_permlane16_swap_b32 %0, %1" : "+v"(a), "+v"(b));
}

// ---------------- fp32 -> bf16 converts + weights + att_mas bit-pack ----------------
// grid (4096, 5): y=0..2 QKV slices; y=3 weights (WQ,WK,WV,WO contiguous); y=4 mask
__global__ __launch_bounds__(256) void cvt_all(const float* __restrict__ a,
                                               const float* __restrict__ b,
                                               const float* __restrict__ c,
                                               const float* __restrict__ wq,
                                               const float* __restrict__ wk,
                                               const float* __restrict__ wv,
                                               const float* __restrict__ wo,
                                               const float* __restrict__ am,
                                               ushort_t* __restrict__ dst,
                                               ushort_t* __restrict__ wdst,
                                               unsigned int* __restrict__ mb, int n4) {
    const int i = blockIdx.x * blockDim.x + threadIdx.x;
    const int yy = blockIdx.y;
    if (yy == 4) {
        // bit-pack att_mas: word t covers att[32t..32t+31]; bit j = (att != 0)
        if (i < NWORDS) {
            const float4* src = (const float4*)am + (size_t)i * 8;
            unsigned int m = 0;
#pragma unroll
            for (int j = 0; j < 8; ++j) {
                const float4 v = src[j];
                m |= (v.x != 0.f ? 1u : 0u) << (4 * j);
                m |= (v.y != 0.f ? 1u : 0u) << (4 * j + 1);
                m |= (v.z != 0.f ? 1u : 0u) << (4 * j + 2);
                m |= (v.w != 0.f ? 1u : 0u) << (4 * j + 3);
            }
            mb[i] = m;
        }
        return;
    }
    if (yy == 3) {
        const int wn4 = DMODEL * DMODEL / 4;          // 65536 float4 per weight
        if (i < 4 * wn4) {
            const int w = i >> 16;
            const float* src = (w == 0) ? wq : (w == 1) ? wk : (w == 2) ? wv : wo;
            const float4 v = ((const float4*)src)[i & (wn4 - 1)];
            ushort4 o;
            o.x = f2bf(v.x); o.y = f2bf(v.y); o.z = f2bf(v.z); o.w = f2bf(v.w);
            ((ushort4*)wdst)[i] = o;
        }
        return;
    }
    const float* src = (yy == 0) ? a : (yy == 1) ? b : c;
    ushort_t* d = dst + (size_t)yy * ((size_t)n4 * 4);
    const float4 v = ((const float4*)src)[i];
    ushort4 o;
    o.x = f2bf(v.x); o.y = f2bf(v.y); o.z = f2bf(v.z); o.w = f2bf(v.w);
    ((ushort4*)d)[i] = o;
}

// ---------------- fused projection GEMM (Q/K/V via blockIdx.z) ----------------
__global__ __launch_bounds__(256) void gemm_proj(const ushort_t* __restrict__ Xall,
                                                 const ushort_t* __restrict__ Wall,
                                                 const float* __restrict__ qmas,
                                                 const float* __restrict__ kmas,
                                                 ushort_t* __restrict__ Qh,
                                                 ushort_t* __restrict__ Kh,
                                                 ushort_t* __restrict__ Vt) {
    __shared__ ushort_t As[128 * 32];
    __shared__ ushort_t Bs[128 * 32];
    const int z = blockIdx.z;
    const ushort_t* X  = Xall + (size_t)z * MROWS * DMODEL;
    const ushort_t* Wb = Wall + (size_t)z * DMODEL * DMODEL;
    const float* rowmask = (z == 0) ? qmas : kmas;

    const int tid  = threadIdx.x;
    const int wave = tid >> 6;
    const int lane = tid & 63;
    const int l16  = lane & 15;
    const int quad = lane >> 4;
    const int wr   = wave >> 1;
    const int wc   = wave & 1;
    const int m0   = blockIdx.x * 128;
    const int n0   = blockIdx.y * 128;
    const int crow = lane >> 2;
    const int koff = (lane & 3) * 8;

    floatx4 acc[4][4];
#pragma unroll
    for (int t = 0; t < 4; ++t)
#pragma unroll
        for (int u = 0; u < 4; ++u) acc[t][u] = (floatx4){0.f, 0.f, 0.f, 0.f};

    for (int k0 = 0; k0 < DMODEL; k0 += 32) {
#pragma unroll
        for (int c2 = 0; c2 < 2; ++c2) {
            const int c = wave * 2 + c2;
            gld16(X  + (size_t)(m0 + c * 16 + crow) * DMODEL + k0 + koff, &As[c * 512]);
            gld16(Wb + (size_t)(n0 + c * 16 + crow) * DMODEL + k0 + koff, &Bs[c * 512]);
        }
        __syncthreads();
        short8 a[4], b[4];
#pragma unroll
        for (int t = 0; t < 4; ++t)
            a[t] = *(const short8*)&As[(wr * 64 + t * 16 + l16) * 32 + quad * 8];
#pragma unroll
        for (int u = 0; u < 4; ++u)
            b[u] = *(const short8*)&Bs[(wc * 64 + u * 16 + l16) * 32 + quad * 8];
#pragma unroll
        for (int t = 0; t < 4; ++t)
#pragma unroll
            for (int u = 0; u < 4; ++u) acc[t][u] = mfma_bf16(a[t], b[u], acc[t][u]);
        __syncthreads();
    }

    float rm[4][4];
#pragma unroll
    for (int t = 0; t < 4; ++t)
#pragma unroll
        for (int r = 0; r < 4; ++r)
            rm[t][r] = rowmask[m0 + wr * 64 + t * 16 + quad * 4 + r];
    if (z == 0) {
        // fold log2(e)/sqrt(dk) into Qh so attn uses exp2(S) directly
#pragma unroll
        for (int t = 0; t < 4; ++t)
#pragma unroll
            for (int r = 0; r < 4; ++r) rm[t][r] *= 0.18033688011112042f;
    }

    const int bb    = m0 >> 11;
    const int nbase = (m0 & (NSEQ - 1)) + wr * 64;
#pragma unroll
    for (int t = 0; t < 4; ++t) {
#pragma unroll
        for (int u = 0; u < 4; ++u) {
            const int d = n0 + wc * 64 + u * 16 + l16;
            const int h = d >> 6, cc = d & 63;
            if (z < 2) {
                ushort_t* dst = (z == 0) ? Qh : Kh;
#pragma unroll
                for (int r = 0; r < 4; ++r) {
                    const int n = nbase + t * 16 + quad * 4 + r;
                    dst[((size_t)(bb * NH + h) * NSEQ + n) * DKH + cc] =
                        f2bf(acc[t][u][r] * rm[t][r]);
                }
            } else {
                ushort4 pk;
                pk.x = f2bf(acc[t][u][0] * rm[t][0]);
                pk.y = f2bf(acc[t][u][1] * rm[t][1]);
                pk.z = f2bf(acc[t][u][2] * rm[t][2]);
                pk.w = f2bf(acc[t][u][3] * rm[t][3]);
                const int n = nbase + t * 16 + quad * 4;
                *(ushort4*)(Vt + ((size_t)(bb * NH + h) * DKH + cc) * NSEQ + n) = pk;
            }
        }
    }
}

// ---------------- output GEMM ----------------
__global__ __launch_bounds__(256) void gemm_out(const ushort_t* __restrict__ X,
                                                const ushort_t* __restrict__ Wb,
                                                const float* __restrict__ rowmask,
                                                float* __restrict__ dst) {
    __shared__ ushort_t As[128 * 32];
    __shared__ ushort_t Bs[128 * 32];
    const int tid  = threadIdx.x;
    const int wave = tid >> 6;
    const int lane = tid & 63;
    const int l16  = lane & 15;
    const int quad = lane >> 4;
    const int wr   = wave >> 1;
    const int wc   = wave & 1;
    const int m0   = blockIdx.x * 128;
    const int n0   = blockIdx.y * 128;
    const int crow = lane >> 2;
    const int koff = (lane & 3) * 8;

    floatx4 acc[4][4];
#pragma unroll
    for (int t = 0; t < 4; ++t)
#pragma unroll
        for (int u = 0; u < 4; ++u) acc[t][u] = (floatx4){0.f, 0.f, 0.f, 0.f};

    for (int k0 = 0; k0 < DMODEL; k0 += 32) {
#pragma unroll
        for (int c2 = 0; c2 < 2; ++c2) {
            const int c = wave * 2 + c2;
            gld16(X  + (size_t)(m0 + c * 16 + crow) * DMODEL + k0 + koff, &As[c * 512]);
            gld16(Wb + (size_t)(n0 + c * 16 + crow) * DMODEL + k0 + koff, &Bs[c * 512]);
        }
        __syncthreads();
        short8 a[4], b[4];
#pragma unroll
        for (int t = 0; t < 4; ++t)
            a[t] = *(const short8*)&As[(wr * 64 + t * 16 + l16) * 32 + quad * 8];
#pragma unroll
        for (int u = 0; u < 4; ++u)
            b[u] = *(const short8*)&Bs[(wc * 64 + u * 16 + l16) * 32 + quad * 8];
#pragma unroll
        for (int t = 0; t < 4; ++t)
#pragma unroll
            for (int u = 0; u < 4; ++u) acc[t][u] = mfma_bf16(a[t], b[u], acc[t][u]);
        __syncthreads();
    }

#pragma unroll
    for (int t = 0; t < 4; ++t) {
#pragma unroll
        for (int r = 0; r < 4; ++r) {
            const int m = m0 + wr * 64 + t * 16 + quad * 4 + r;
            const float rm = rowmask[m];
#pragma unroll
            for (int u = 0; u < 4; ++u) {
                const int d = n0 + wc * 64 + u * 16 + l16;
                dst[(size_t)m * DMODEL + d] = acc[t][u][r] * rm;
            }
        }
    }
}

// ---------------- flash attention: 128-q blocks, 2 q-groups/wave, in-register P ----------------
// Qh (pre-scaled by log2e/8), Kh: [b][h][n][64] bf16;  Vt: [b][h][c][n] bf16;
// Mb: bit-packed att_mas (in d_out, overwritten later by gemm_out); kmas fp32.
// S^T (mfma(K,Q)): lane (l16,quad_s) reg r holds P[key=fr*16+quad_s*4+r][q=l16].
// PV A-operand needs lane (l16,quad_d): P[q=l16][key=kf*32+quad_d*8+j].
// That transpose = quad redistribution at fixed l16: after cvt_pk (XE,YE from
// fr=2kf; XO,YO from fr=2kf+1): permlane32_swap(XE,XO) then permlane16_swap(XE,XO)
// yields (w0,w2); same for Y -> (w1,w3). pf = {w0,w1,w2,w3}. No LDS, no barriers.
__global__ __launch_bounds__(256) void attn_kernel(const ushort_t* __restrict__ Qh,
                                                   const ushort_t* __restrict__ Kh,
                                                   const ushort_t* __restrict__ Vt,
                                                   const unsigned int* __restrict__ Mb,
                                                   const float* __restrict__ kmas,
                                                   ushort_t* __restrict__ y) {
    __shared__ __align__(16) ushort_t Ks[128 * 72];      // 18432 B
    __shared__ __align__(16) ushort_t Vs[64 * 136];      // 17408 B (total 35840)

    const int tid  = threadIdx.x;
    const int lane = tid & 63;
    const int wave = tid >> 6;
    const int l16  = lane & 15;
    const int quad = lane >> 4;
    const int h    = blockIdx.y;
    const int b    = blockIdx.z;
    const int qw   = blockIdx.x * 128 + wave * 32;   // this wave's 32 q-rows

    const ushort_t* Kb = Kh + (size_t)(b * NH + h) * NSEQ * DKH;
    const ushort_t* Vb = Vt + (size_t)(b * NH + h) * DKH * NSEQ;
    // per-lane mask rows: q = qw + l16 (group 0) and qw + 16 + l16 (group 1)
    const uint4* Mv0 = (const uint4*)(Mb + ((size_t)(b * NSEQ + qw) + l16) * NW32);
    const uint4* Mv1 = (const uint4*)(Mb + ((size_t)(b * NSEQ + qw) + 16 + l16) * NW32);

    const ushort_t* Qp0 = Qh + ((size_t)((b * NH + h) * NSEQ) + qw + l16) * DKH + quad * 8;
    const ushort_t* Qp1 = Qp0 + 16 * DKH;
    const short8 qf0a = *(const short8*)Qp0;
    const short8 qf0b = *(const short8*)(Qp0 + 32);
    const short8 qf1a = *(const short8*)Qp1;
    const short8 qf1b = *(const short8*)(Qp1 + 32);

    // all-ones bf16 B-operand for row-sum MFMA (bf16 1.0 = 0x3F80)
    const short8 ones = {(short)0x3F80, (short)0x3F80, (short)0x3F80, (short)0x3F80,
                         (short)0x3F80, (short)0x3F80, (short)0x3F80, (short)0x3F80};

    floatx4 accA[4], accB[4];
    floatx4 accL0 = (floatx4){0.f, 0.f, 0.f, 0.f};   // row-sums l, group 0
    floatx4 accL1 = (floatx4){0.f, 0.f, 0.f, 0.f};   // row-sums l, group 1
#pragma unroll
    for (int ct = 0; ct < 4; ++ct) {
        accA[ct] = (floatx4){0.f, 0.f, 0.f, 0.f};
        accB[ct] = (floatx4){0.f, 0.f, 0.f, 0.f};
    }

// S fragment FR (compile-time after unroll) -> packed P words for both groups
#define SFRAG(FR, PX0, PY0, PX1, PY1) do {                                         \
    const short8 ka = *(const short8*)&Ks[((FR) * 16 + l16) * 72 + quad * 8];      \
    const short8 kb = *(const short8*)&Ks[((FR) * 16 + l16) * 72 + 32 + quad * 8]; \
    floatx4 s0 = {0.f, 0.f, 0.f, 0.f};                                             \
    s0 = mfma_bf16(ka, qf0a, s0);                                                  \
    s0 = mfma_bf16(kb, qf0b, s0);                                                  \
    floatx4 s1 = {0.f, 0.f, 0.f, 0.f};                                             \
    s1 = mfma_bf16(ka, qf1a, s1);                                                  \
    s1 = mfma_bf16(kb, qf1b, s1);                                                  \
    float p0[4], p1[4];                                                            \
    _Pragma("unroll")                                                              \
    for (int r = 0; r < 4; ++r) {                                                  \
        const int bitp = (((FR) & 1) << 4) + r;                                    \
        const unsigned m0m =                                                       \
            (unsigned)__builtin_amdgcn_sbfe((int)wsh0[(FR) >> 1], bitp, 1);        \
        const unsigned m1m =                                                       \
            (unsigned)__builtin_amdgcn_sbfe((int)wsh1[(FR) >> 1], bitp, 1);        \
        p0[r] = __builtin_bit_cast(float,                                          \
                    __builtin_bit_cast(unsigned, fexp2(s0[r])) & m0m);             \
        p1[r] = __builtin_bit_cast(float,                                          \
                    __builtin_bit_cast(unsigned, fexp2(s1[r])) & m1m);             \
    }                                                                              \
    PX0 = cvt_pk_bf16(p0[0], p0[1]); PY0 = cvt_pk_bf16(p0[2], p0[3]);              \
    PX1 = cvt_pk_bf16(p1[0], p1[1]); PY1 = cvt_pk_bf16(p1[2], p1[3]);              \
} while (0)

    for (int kt = 0; kt < NSEQ / 128; ++kt) {
        const int k0 = kt * 128;

        // ---- gather staging data into VGPRs (coalesced 16B/lane) ----
        short8 kv[4], vv[4];
#pragma unroll
        for (int i = 0; i < 4; ++i) {
            const int c = tid + i * 256;
            kv[i] = *(const short8*)(Kb + (size_t)(k0 + (c >> 3)) * DKH + (c & 7) * 8);
        }
#pragma unroll
        for (int i = 0; i < 4; ++i) {
            const int c = tid + i * 256;
            vv[i] = *(const short8*)(Vb + (size_t)(c >> 4) * NSEQ + k0 + (c & 15) * 8);
        }
        const uint4 mw0 = Mv0[kt];
        const uint4 mw1 = Mv1[kt];

        __syncthreads();   // (a) previous tile's LDS reads complete
#pragma unroll
        for (int i = 0; i < 4; ++i) {
            const int c = tid + i * 256;
            *(short8*)&Ks[(c >> 3) * 72 + (c & 7) * 8] = kv[i];
        }
#pragma unroll
        for (int i = 0; i < 4; ++i) {
            const int c = tid + i * 256;
            *(short8*)&Vs[(c >> 4) * 136 + (c & 15) * 8] = vv[i];
        }
        __syncthreads();   // (b) tile staged

        const unsigned int wsh0[4] = {mw0.x >> (quad * 4), mw0.y >> (quad * 4),
                                      mw0.z >> (quad * 4), mw0.w >> (quad * 4)};
        const unsigned int wsh1[4] = {mw1.x >> (quad * 4), mw1.y >> (quad * 4),
                                      mw1.z >> (quad * 4), mw1.w >> (quad * 4)};

        // ---- fused per-kf: S (2 frags) -> softmax -> permlane transpose -> l + PV ----
#pragma unroll
        for (int kf = 0; kf < 4; ++kf) {
            unsigned xe0, ye0, xo0, yo0;   // group 0: fr even / odd packed words
            unsigned xe1, ye1, xo1, yo1;   // group 1
            SFRAG(kf * 2,     xe0, ye0, xe1, ye1);
            SFRAG(kf * 2 + 1, xo0, yo0, xo1, yo1);

            permlane32_swap(xe0, xo0); permlane32_swap(ye0, yo0);
            permlane16_swap(xe0, xo0); permlane16_swap(ye0, yo0);
            permlane32_swap(xe1, xo1); permlane32_swap(ye1, yo1);
            permlane16_swap(xe1, xo1); permlane16_swap(ye1, yo1);

            const uint4 u0 = {xe0, ye0, xo0, yo0};
            const uint4 u1 = {xe1, ye1, xo1, yo1};
            const short8 pf0 = __builtin_bit_cast(short8, u0);
            const short8 pf1 = __builtin_bit_cast(short8, u1);

            // l += P.1 on the MFMA pipe
            accL0 = mfma_bf16(pf0, ones, accL0);
            accL1 = mfma_bf16(pf1, ones, accL1);

            // O += P.V : each V fragment read once -> both q-groups
#pragma unroll
            for (int ct = 0; ct < 4; ++ct) {
                const short8 vb =
                    *(const short8*)&Vs[(ct * 16 + l16) * 136 + kf * 32 + quad * 8];
                accA[ct] = mfma_bf16(pf0, vb, accA[ct]);
                accB[ct] = mfma_bf16(pf1, vb, accB[ct]);
            }
        }
    }
#undef SFRAG

    // ---- epilogue: l is in accL at exactly (q = qw + quad*4 + r); no shuffles ----
#pragma unroll
    for (int r = 0; r < 4; ++r) {
        const int q0 = qw + quad * 4 + r;
        const int q1 = q0 + 16;
        const float sc0 = kmas[b * NSEQ + q0] / accL0[r];
        const float sc1 = kmas[b * NSEQ + q1] / accL1[r];
#pragma unroll
        for (int ct = 0; ct < 4; ++ct) {
            y[(size_t)(b * NSEQ + q0) * DMODEL + h * DKH + ct * 16 + l16] =
                f2bf(accA[ct][r] * sc0);
            y[(size_t)(b * NSEQ + q1) * DMODEL + h * DKH + ct * 16 + l16] =
                f2bf(accB[ct][r] * sc1);
        }
    }
}

extern "C" void kernel_launch(void* const* d_in, const int* in_sizes, int n_in,
                              void* d_out, int out_size, void* d_ws, size_t ws_size,
                              hipStream_t stream) {
    (void)in_sizes; (void)n_in; (void)out_size; (void)ws_size;
    const float* Q  = (const float*)d_in[0];
    const float* K  = (const float*)d_in[1];
    const float* V  = (const float*)d_in[2];
    const float* qm = (const float*)d_in[3];
    const float* km = (const float*)d_in[4];
    const float* am = (const float*)d_in[5];
    const float* WQ = (const float*)d_in[6];
    const float* WK = (const float*)d_in[7];
    const float* WV = (const float*)d_in[8];
    const float* WO = (const float*)d_in[9];

    const size_t XN = (size_t)MROWS * DMODEL;        // 4,194,304
    const size_t WN = (size_t)DMODEL * DMODEL;       // 262,144
    ushort_t* Xbf = (ushort_t*)d_ws;                 // Q,K,V bf16: 3*XN
    ushort_t* Wbf = Xbf + 3 * XN;                    // WQ,WK,WV,WO bf16: 4*WN
    ushort_t* WOb = Wbf + 3 * WN;
    ushort_t* Qh  = Wbf + 4 * WN;
    ushort_t* Kh  = Qh + XN;
    ushort_t* Vt  = Kh + XN;
    ushort_t* y   = Vt + XN;
    // packed mask lives in d_out (2 MB of 16 MB); gemm_out fully overwrites d_out afterwards
    unsigned int* Mbits = (unsigned int*)d_out;
    float* out = (float*)d_out;

    hipLaunchKernelGGL(cvt_all, dim3(4096, 5), dim3(256), 0, stream,
                       Q, K, V, WQ, WK, WV, WO, am, Xbf, Wbf, Mbits, (int)(XN / 4));

    hipLaunchKernelGGL(gemm_proj, dim3(MROWS / 128, DMODEL / 128, 3), dim3(256), 0, stream,
                       Xbf, Wbf, qm, km, Qh, Kh, Vt);

    hipLaunchKernelGGL(attn_kernel, dim3(NSEQ / 128, NH, BS_), dim3(256), 0, stream,
                       Qh, Kh, Vt, Mbits, km, y);

    hipLaunchKernelGGL(gemm_out, dim3(MROWS / 128, DMODEL / 128), dim3(256), 0, stream,
                       y, WOb, km, out);
}

// Round 10
// 257.566 us; speedup vs baseline: 1.3787x; 1.0150x over previous
//
#include <hip/hip_runtime.h>

// MultiHeadAttention: BS=4, N=2048, D=512, H=8, DK=64. fp32 in/out, bf16 MFMA compute.
// Round 15: GEMM kernels (the ~130us pot): BK 32->64 halves barrier-pairs per block
// (2-phase GEMM critical path is ~72% stage+vmcnt+barrier), and both-sides XOR
// swizzle (linear gld16 dest + pre-swizzled global source col + swizzled ds_read)
// takes b128 fragment reads from 16-way to the 8-lane/group floor.
// attn (R14 structure: 2 q-groups/wave, permlane P transpose, MFMA l) untouched.

#define BS_    4
#define NSEQ   2048
#define DMODEL 512
#define NH     8
#define DKH    64
#define MROWS  (BS_ * NSEQ)   // 8192
#define NW32   (NSEQ / 32)    // 64 mask words per row
#define NWORDS (BS_ * NSEQ * NSEQ / 32)  // 524288 packed mask words

typedef unsigned short ushort_t;
typedef __attribute__((ext_vector_type(8))) short short8;   // 8 bf16 (4 VGPRs)
typedef __attribute__((ext_vector_type(4))) float floatx4;  // 4 fp32 acc

__device__ __forceinline__ ushort_t f2bf(float f) {
    unsigned int x = __builtin_bit_cast(unsigned int, f);
    unsigned int lsb = (x >> 16) & 1u;
    x += 0x7fffu + lsb;          // round-to-nearest-even
    return (ushort_t)(x >> 16);
}
__device__ __forceinline__ floatx4 mfma_bf16(short8 a, short8 b, floatx4 c) {
    return __builtin_amdgcn_mfma_f32_16x16x32_bf16(a, b, c, 0, 0, 0);
}
__device__ __forceinline__ void gld16(const ushort_t* g, ushort_t* l) {
    __builtin_amdgcn_global_load_lds(
        (const __attribute__((address_space(1))) unsigned int*)g,
        (__attribute__((address_space(3))) unsigned int*)l, 16, 0, 0);
}
__device__ __forceinline__ unsigned int cvt_pk_bf16(float lo, float hi) {
    unsigned int r;
    asm("v_cvt_pk_bf16_f32 %0, %1, %2" : "=v"(r) : "v"(lo), "v"(hi));
    return r;
}
__device__ __forceinline__ float fexp2(float x) {
#if __has_builtin(__builtin_amdgcn_exp2f)
    return __builtin_amdgcn_exp2f(x);   // raw v_exp_f32
#else
    return exp2f(x);
#endif
}
// gfx950: swap a[32:63] <-> b[0:31]
__device__ __forceinline__ void permlane32_swap(unsigned& a, unsigned& b) {
    asm volatile("v_permlane32_swap_b32 %0, %1" : "+v"(a), "+v"(b));
}
// gfx950: swap a[16:31]<->b[0:15] and a[48:63]<->b[32:47]
__device__ __forceinline__ void permlane16_swap(unsigned& a, unsigned& b) {
    asm volatile("v_permlane16_swap_b32 %0, %1" : "+v"(a), "+v"(b));
}

// ---------------- fp32 -> bf16 converts + weights + att_mas bit-pack ----------------
// grid (4096, 5): y=0..2 QKV slices; y=3 weights (WQ,WK,WV,WO contiguous); y=4 mask
__global__ __launch_bounds__(256) void cvt_all(const float* __restrict__ a,
                                               const float* __restrict__ b,
                                               const float* __restrict__ c,
                                               const float* __restrict__ wq,
                                               const float* __restrict__ wk,
                                               const float* __restrict__ wv,
                                               const float* __restrict__ wo,
                                               const float* __restrict__ am,
                                               ushort_t* __restrict__ dst,
                                               ushort_t* __restrict__ wdst,
                                               unsigned int* __restrict__ mb, int n4) {
    const int i = blockIdx.x * blockDim.x + threadIdx.x;
    const int yy = blockIdx.y;
    if (yy == 4) {
        // bit-pack att_mas: word t covers att[32t..32t+31]; bit j = (att != 0)
        if (i < NWORDS) {
            const float4* src = (const float4*)am + (size_t)i * 8;
            unsigned int m = 0;
#pragma unroll
            for (int j = 0; j < 8; ++j) {
                const float4 v = src[j];
                m |= (v.x != 0.f ? 1u : 0u) << (4 * j);
                m |= (v.y != 0.f ? 1u : 0u) << (4 * j + 1);
                m |= (v.z != 0.f ? 1u : 0u) << (4 * j + 2);
                m |= (v.w != 0.f ? 1u : 0u) << (4 * j + 3);
            }
            mb[i] = m;
        }
        return;
    }
    if (yy == 3) {
        const int wn4 = DMODEL * DMODEL / 4;          // 65536 float4 per weight
        if (i < 4 * wn4) {
            const int w = i >> 16;
            const float* src = (w == 0) ? wq : (w == 1) ? wk : (w == 2) ? wv : wo;
            const float4 v = ((const float4*)src)[i & (wn4 - 1)];
            ushort4 o;
            o.x = f2bf(v.x); o.y = f2bf(v.y); o.z = f2bf(v.z); o.w = f2bf(v.w);
            ((ushort4*)wdst)[i] = o;
        }
        return;
    }
    const float* src = (yy == 0) ? a : (yy == 1) ? b : c;
    ushort_t* d = dst + (size_t)yy * ((size_t)n4 * 4);
    const float4 v = ((const float4*)src)[i];
    ushort4 o;
    o.x = f2bf(v.x); o.y = f2bf(v.y); o.z = f2bf(v.z); o.w = f2bf(v.w);
    ((ushort4*)d)[i] = o;
}

// ---------------- fused projection GEMM (Q/K/V via blockIdx.z), BK=64, swizzled ----------------
// LDS layout: As/Bs are 128 rows x 64 elem (128B rows). Physical 16B-slot p of row r
// holds logical col16 g = p ^ (r&7) (both-sides swizzle: linear gld16 dest, global
// source col pre-XOR'd, ds_read col XOR'd). Fragment reads hit the b128 bank floor.
__global__ __launch_bounds__(256) void gemm_proj(const ushort_t* __restrict__ Xall,
                                                 const ushort_t* __restrict__ Wall,
                                                 const float* __restrict__ qmas,
                                                 const float* __restrict__ kmas,
                                                 ushort_t* __restrict__ Qh,
                                                 ushort_t* __restrict__ Kh,
                                                 ushort_t* __restrict__ Vt) {
    __shared__ ushort_t As[128 * 64];   // 16 KB
    __shared__ ushort_t Bs[128 * 64];   // 16 KB
    const int z = blockIdx.z;
    const ushort_t* X  = Xall + (size_t)z * MROWS * DMODEL;
    const ushort_t* Wb = Wall + (size_t)z * DMODEL * DMODEL;
    const float* rowmask = (z == 0) ? qmas : kmas;

    const int tid  = threadIdx.x;
    const int wave = tid >> 6;
    const int lane = tid & 63;
    const int l16  = lane & 15;
    const int quad = lane >> 4;
    const int wr   = wave >> 1;
    const int wc   = wave & 1;
    const int m0   = blockIdx.x * 128;
    const int n0   = blockIdx.y * 128;
    const int srow = tid >> 3;                              // 0..31
    const int scol = 8 * ((tid & 7) ^ ((tid >> 3) & 7));    // pre-swizzled source col

    floatx4 acc[4][4];
#pragma unroll
    for (int t = 0; t < 4; ++t)
#pragma unroll
        for (int u = 0; u < 4; ++u) acc[t][u] = (floatx4){0.f, 0.f, 0.f, 0.f};

    for (int k0 = 0; k0 < DMODEL; k0 += 64) {
#pragma unroll
        for (int i = 0; i < 4; ++i) {
            const int row = i * 32 + srow;
            gld16(X  + (size_t)(m0 + row) * DMODEL + k0 + scol, &As[i * 2048 + tid * 8]);
            gld16(Wb + (size_t)(n0 + row) * DMODEL + k0 + scol, &Bs[i * 2048 + tid * 8]);
        }
        __syncthreads();
#pragma unroll
        for (int kk = 0; kk < 64; kk += 32) {
            short8 a[4], b[4];
#pragma unroll
            for (int t = 0; t < 4; ++t) {
                const int pc = ((((kk >> 3) | quad) ^ (l16 & 7)) * 8);
                a[t] = *(const short8*)&As[(wr * 64 + t * 16 + l16) * 64 + pc];
            }
#pragma unroll
            for (int u = 0; u < 4; ++u) {
                const int pc = ((((kk >> 3) | quad) ^ (l16 & 7)) * 8);
                b[u] = *(const short8*)&Bs[(wc * 64 + u * 16 + l16) * 64 + pc];
            }
#pragma unroll
            for (int t = 0; t < 4; ++t)
#pragma unroll
                for (int u = 0; u < 4; ++u) acc[t][u] = mfma_bf16(a[t], b[u], acc[t][u]);
        }
        __syncthreads();
    }

    float rm[4][4];
#pragma unroll
    for (int t = 0; t < 4; ++t)
#pragma unroll
        for (int r = 0; r < 4; ++r)
            rm[t][r] = rowmask[m0 + wr * 64 + t * 16 + quad * 4 + r];
    if (z == 0) {
        // fold log2(e)/sqrt(dk) into Qh so attn uses exp2(S) directly
#pragma unroll
        for (int t = 0; t < 4; ++t)
#pragma unroll
            for (int r = 0; r < 4; ++r) rm[t][r] *= 0.18033688011112042f;
    }

    const int bb    = m0 >> 11;
    const int nbase = (m0 & (NSEQ - 1)) + wr * 64;
#pragma unroll
    for (int t = 0; t < 4; ++t) {
#pragma unroll
        for (int u = 0; u < 4; ++u) {
            const int d = n0 + wc * 64 + u * 16 + l16;
            const int h = d >> 6, cc = d & 63;
            if (z < 2) {
                ushort_t* dst = (z == 0) ? Qh : Kh;
#pragma unroll
                for (int r = 0; r < 4; ++r) {
                    const int n = nbase + t * 16 + quad * 4 + r;
                    dst[((size_t)(bb * NH + h) * NSEQ + n) * DKH + cc] =
                        f2bf(acc[t][u][r] * rm[t][r]);
                }
            } else {
                ushort4 pk;
                pk.x = f2bf(acc[t][u][0] * rm[t][0]);
                pk.y = f2bf(acc[t][u][1] * rm[t][1]);
                pk.z = f2bf(acc[t][u][2] * rm[t][2]);
                pk.w = f2bf(acc[t][u][3] * rm[t][3]);
                const int n = nbase + t * 16 + quad * 4;
                *(ushort4*)(Vt + ((size_t)(bb * NH + h) * DKH + cc) * NSEQ + n) = pk;
            }
        }
    }
}

// ---------------- output GEMM, BK=64, swizzled ----------------
__global__ __launch_bounds__(256) void gemm_out(const ushort_t* __restrict__ X,
                                                const ushort_t* __restrict__ Wb,
                                                const float* __restrict__ rowmask,
                                                float* __restrict__ dst) {
    __shared__ ushort_t As[128 * 64];
    __shared__ ushort_t Bs[128 * 64];
    const int tid  = threadIdx.x;
    const int wave = tid >> 6;
    const int lane = tid & 63;
    const int l16  = lane & 15;
    const int quad = lane >> 4;
    const int wr   = wave >> 1;
    const int wc   = wave & 1;
    const int m0   = blockIdx.x * 128;
    const int n0   = blockIdx.y * 128;
    const int srow = tid >> 3;
    const int scol = 8 * ((tid & 7) ^ ((tid >> 3) & 7));

    floatx4 acc[4][4];
#pragma unroll
    for (int t = 0; t < 4; ++t)
#pragma unroll
        for (int u = 0; u < 4; ++u) acc[t][u] = (floatx4){0.f, 0.f, 0.f, 0.f};

    for (int k0 = 0; k0 < DMODEL; k0 += 64) {
#pragma unroll
        for (int i = 0; i < 4; ++i) {
            const int row = i * 32 + srow;
            gld16(X  + (size_t)(m0 + row) * DMODEL + k0 + scol, &As[i * 2048 + tid * 8]);
            gld16(Wb + (size_t)(n0 + row) * DMODEL + k0 + scol, &Bs[i * 2048 + tid * 8]);
        }
        __syncthreads();
#pragma unroll
        for (int kk = 0; kk < 64; kk += 32) {
            short8 a[4], b[4];
#pragma unroll
            for (int t = 0; t < 4; ++t) {
                const int pc = ((((kk >> 3) | quad) ^ (l16 & 7)) * 8);
                a[t] = *(const short8*)&As[(wr * 64 + t * 16 + l16) * 64 + pc];
            }
#pragma unroll
            for (int u = 0; u < 4; ++u) {
                const int pc = ((((kk >> 3) | quad) ^ (l16 & 7)) * 8);
                b[u] = *(const short8*)&Bs[(wc * 64 + u * 16 + l16) * 64 + pc];
            }
#pragma unroll
            for (int t = 0; t < 4; ++t)
#pragma unroll
                for (int u = 0; u < 4; ++u) acc[t][u] = mfma_bf16(a[t], b[u], acc[t][u]);
        }
        __syncthreads();
    }

#pragma unroll
    for (int t = 0; t < 4; ++t) {
#pragma unroll
        for (int r = 0; r < 4; ++r) {
            const int m = m0 + wr * 64 + t * 16 + quad * 4 + r;
            const float rm = rowmask[m];
#pragma unroll
            for (int u = 0; u < 4; ++u) {
                const int d = n0 + wc * 64 + u * 16 + l16;
                dst[(size_t)m * DMODEL + d] = acc[t][u][r] * rm;
            }
        }
    }
}

// ---------------- flash attention: 128-q blocks, 2 q-groups/wave, in-register P ----------------
// (unchanged from R14 — see that round's notes; 64.4 us, MfmaUtil 23.8%)
__global__ __launch_bounds__(256) void attn_kernel(const ushort_t* __restrict__ Qh,
                                                   const ushort_t* __restrict__ Kh,
                                                   const ushort_t* __restrict__ Vt,
                                                   const unsigned int* __restrict__ Mb,
                                                   const float* __restrict__ kmas,
                                                   ushort_t* __restrict__ y) {
    __shared__ __align__(16) ushort_t Ks[128 * 72];      // 18432 B
    __shared__ __align__(16) ushort_t Vs[64 * 136];      // 17408 B (total 35840)

    const int tid  = threadIdx.x;
    const int lane = tid & 63;
    const int wave = tid >> 6;
    const int l16  = lane & 15;
    const int quad = lane >> 4;
    const int h    = blockIdx.y;
    const int b    = blockIdx.z;
    const int qw   = blockIdx.x * 128 + wave * 32;   // this wave's 32 q-rows

    const ushort_t* Kb = Kh + (size_t)(b * NH + h) * NSEQ * DKH;
    const ushort_t* Vb = Vt + (size_t)(b * NH + h) * DKH * NSEQ;
    // per-lane mask rows: q = qw + l16 (group 0) and qw + 16 + l16 (group 1)
    const uint4* Mv0 = (const uint4*)(Mb + ((size_t)(b * NSEQ + qw) + l16) * NW32);
    const uint4* Mv1 = (const uint4*)(Mb + ((size_t)(b * NSEQ + qw) + 16 + l16) * NW32);

    const ushort_t* Qp0 = Qh + ((size_t)((b * NH + h) * NSEQ) + qw + l16) * DKH + quad * 8;
    const ushort_t* Qp1 = Qp0 + 16 * DKH;
    const short8 qf0a = *(const short8*)Qp0;
    const short8 qf0b = *(const short8*)(Qp0 + 32);
    const short8 qf1a = *(const short8*)Qp1;
    const short8 qf1b = *(const short8*)(Qp1 + 32);

    // all-ones bf16 B-operand for row-sum MFMA (bf16 1.0 = 0x3F80)
    const short8 ones = {(short)0x3F80, (short)0x3F80, (short)0x3F80, (short)0x3F80,
                         (short)0x3F80, (short)0x3F80, (short)0x3F80, (short)0x3F80};

    floatx4 accA[4], accB[4];
    floatx4 accL0 = (floatx4){0.f, 0.f, 0.f, 0.f};   // row-sums l, group 0
    floatx4 accL1 = (floatx4){0.f, 0.f, 0.f, 0.f};   // row-sums l, group 1
#pragma unroll
    for (int ct = 0; ct < 4; ++ct) {
        accA[ct] = (floatx4){0.f, 0.f, 0.f, 0.f};
        accB[ct] = (floatx4){0.f, 0.f, 0.f, 0.f};
    }

// S fragment FR (compile-time after unroll) -> packed P words for both groups
#define SFRAG(FR, PX0, PY0, PX1, PY1) do {                                         \
    const short8 ka = *(const short8*)&Ks[((FR) * 16 + l16) * 72 + quad * 8];      \
    const short8 kb = *(const short8*)&Ks[((FR) * 16 + l16) * 72 + 32 + quad * 8]; \
    floatx4 s0 = {0.f, 0.f, 0.f, 0.f};                                             \
    s0 = mfma_bf16(ka, qf0a, s0);                                                  \
    s0 = mfma_bf16(kb, qf0b, s0);                                                  \
    floatx4 s1 = {0.f, 0.f, 0.f, 0.f};                                             \
    s1 = mfma_bf16(ka, qf1a, s1);                                                  \
    s1 = mfma_bf16(kb, qf1b, s1);                                                  \
    float p0[4], p1[4];                                                            \
    _Pragma("unroll")                                                              \
    for (int r = 0; r < 4; ++r) {                                                  \
        const int bitp = (((FR) & 1) << 4) + r;                                    \
        const unsigned m0m =                                                       \
            (unsigned)__builtin_amdgcn_sbfe((int)wsh0[(FR) >> 1], bitp, 1);        \
        const unsigned m1m =                                                       \
            (unsigned)__builtin_amdgcn_sbfe((int)wsh1[(FR) >> 1], bitp, 1);        \
        p0[r] = __builtin_bit_cast(float,                                          \
                    __builtin_bit_cast(unsigned, fexp2(s0[r])) & m0m);             \
        p1[r] = __builtin_bit_cast(float,                                          \
                    __builtin_bit_cast(unsigned, fexp2(s1[r])) & m1m);             \
    }                                                                              \
    PX0 = cvt_pk_bf16(p0[0], p0[1]); PY0 = cvt_pk_bf16(p0[2], p0[3]);              \
    PX1 = cvt_pk_bf16(p1[0], p1[1]); PY1 = cvt_pk_bf16(p1[2], p1[3]);              \
} while (0)

    for (int kt = 0; kt < NSEQ / 128; ++kt) {
        const int k0 = kt * 128;

        // ---- gather staging data into VGPRs (coalesced 16B/lane) ----
        short8 kv[4], vv[4];
#pragma unroll
        for (int i = 0; i < 4; ++i) {
            const int c = tid + i * 256;
            kv[i] = *(const short8*)(Kb + (size_t)(k0 + (c >> 3)) * DKH + (c & 7) * 8);
        }
#pragma unroll
        for (int i = 0; i < 4; ++i) {
            const int c = tid + i * 256;
            vv[i] = *(const short8*)(Vb + (size_t)(c >> 4) * NSEQ + k0 + (c & 15) * 8);
        }
        const uint4 mw0 = Mv0[kt];
        const uint4 mw1 = Mv1[kt];

        __syncthreads();   // (a) previous tile's LDS reads complete
#pragma unroll
        for (int i = 0; i < 4; ++i) {
            const int c = tid + i * 256;
            *(short8*)&Ks[(c >> 3) * 72 + (c & 7) * 8] = kv[i];
        }
#pragma unroll
        for (int i = 0; i < 4; ++i) {
            const int c = tid + i * 256;
            *(short8*)&Vs[(c >> 4) * 136 + (c & 15) * 8] = vv[i];
        }
        __syncthreads();   // (b) tile staged

        const unsigned int wsh0[4] = {mw0.x >> (quad * 4), mw0.y >> (quad * 4),
                                      mw0.z >> (quad * 4), mw0.w >> (quad * 4)};
        const unsigned int wsh1[4] = {mw1.x >> (quad * 4), mw1.y >> (quad * 4),
                                      mw1.z >> (quad * 4), mw1.w >> (quad * 4)};

        // ---- fused per-kf: S (2 frags) -> softmax -> permlane transpose -> l + PV ----
#pragma unroll
        for (int kf = 0; kf < 4; ++kf) {
            unsigned xe0, ye0, xo0, yo0;   // group 0: fr even / odd packed words
            unsigned xe1, ye1, xo1, yo1;   // group 1
            SFRAG(kf * 2,     xe0, ye0, xe1, ye1);
            SFRAG(kf * 2 + 1, xo0, yo0, xo1, yo1);

            permlane32_swap(xe0, xo0); permlane32_swap(ye0, yo0);
            permlane16_swap(xe0, xo0); permlane16_swap(ye0, yo0);
            permlane32_swap(xe1, xo1); permlane32_swap(ye1, yo1);
            permlane16_swap(xe1, xo1); permlane16_swap(ye1, yo1);

            const uint4 u0 = {xe0, ye0, xo0, yo0};
            const uint4 u1 = {xe1, ye1, xo1, yo1};
            const short8 pf0 = __builtin_bit_cast(short8, u0);
            const short8 pf1 = __builtin_bit_cast(short8, u1);

            // l += P.1 on the MFMA pipe
            accL0 = mfma_bf16(pf0, ones, accL0);
            accL1 = mfma_bf16(pf1, ones, accL1);

            // O += P.V : each V fragment read once -> both q-groups
#pragma unroll
            for (int ct = 0; ct < 4; ++ct) {
                const short8 vb =
                    *(const short8*)&Vs[(ct * 16 + l16) * 136 + kf * 32 + quad * 8];
                accA[ct] = mfma_bf16(pf0, vb, accA[ct]);
                accB[ct] = mfma_bf16(pf1, vb, accB[ct]);
            }
        }
    }
#undef SFRAG

    // ---- epilogue: l is in accL at exactly (q = qw + quad*4 + r); no shuffles ----
#pragma unroll
    for (int r = 0; r < 4; ++r) {
        const int q0 = qw + quad * 4 + r;
        const int q1 = q0 + 16;
        const float sc0 = kmas[b * NSEQ + q0] / accL0[r];
        const float sc1 = kmas[b * NSEQ + q1] / accL1[r];
#pragma unroll
        for (int ct = 0; ct < 4; ++ct) {
            y[(size_t)(b * NSEQ + q0) * DMODEL + h * DKH + ct * 16 + l16] =
                f2bf(accA[ct][r] * sc0);
            y[(size_t)(b * NSEQ + q1) * DMODEL + h * DKH + ct * 16 + l16] =
                f2bf(accB[ct][r] * sc1);
        }
    }
}

extern "C" void kernel_launch(void* const* d_in, const int* in_sizes, int n_in,
                              void* d_out, int out_size, void* d_ws, size_t ws_size,
                              hipStream_t stream) {
    (void)in_sizes; (void)n_in; (void)out_size; (void)ws_size;
    const float* Q  = (const float*)d_in[0];
    const float* K  = (const float*)d_in[1];
    const float* V  = (const float*)d_in[2];
    const float* qm = (const float*)d_in[3];
    const float* km = (const float*)d_in[4];
    const float* am = (const float*)d_in[5];
    const float* WQ = (const float*)d_in[6];
    const float* WK = (const float*)d_in[7];
    const float* WV = (const float*)d_in[8];
    const float* WO = (const float*)d_in[9];

    const size_t XN = (size_t)MROWS * DMODEL;        // 4,194,304
    const size_t WN = (size_t)DMODEL * DMODEL;       // 262,144
    ushort_t* Xbf = (ushort_t*)d_ws;                 // Q,K,V bf16: 3*XN
    ushort_t* Wbf = Xbf + 3 * XN;                    // WQ,WK,WV,WO bf16: 4*WN
    ushort_t* WOb = Wbf + 3 * WN;
    ushort_t* Qh  = Wbf + 4 * WN;
    ushort_t* Kh  = Qh + XN;
    ushort_t* Vt  = Kh + XN;
    ushort_t* y   = Vt + XN;
    // packed mask lives in d_out (2 MB of 16 MB); gemm_out fully overwrites d_out afterwards
    unsigned int* Mbits = (unsigned int*)d_out;
    float* out = (float*)d_out;

    hipLaunchKernelGGL(cvt_all, dim3(4096, 5), dim3(256), 0, stream,
                       Q, K, V, WQ, WK, WV, WO, am, Xbf, Wbf, Mbits, (int)(XN / 4));

    hipLaunchKernelGGL(gemm_proj, dim3(MROWS / 128, DMODEL / 128, 3), dim3(256), 0, stream,
                       Xbf, Wbf, qm, km, Qh, Kh, Vt);

    hipLaunchKernelGGL(attn_kernel, dim3(NSEQ / 128, NH, BS_), dim3(256), 0, stream,
                       Qh, Kh, Vt, Mbits, km, y);

    hipLaunchKernelGGL(gemm_out, dim3(MROWS / 128, DMODEL / 128), dim3(256), 0, stream,
                       y, WOb, km, out);
}

// Round 11
// 243.787 us; speedup vs baseline: 1.4566x; 1.0565x over previous
//
#include <hip/hip_runtime.h>

// MultiHeadAttention: BS=4, N=2048, D=512, H=8, DK=64. fp32 in/out, bf16 MFMA compute.
// Round 16: the ~150us GEMM pot is an OCCUPANCY hole, not pipes: 128x128 tiles on
// this skinny shape give gemm_out 256 blocks = 1 block/CU (1 wave/SIMD, no TLP).
// Tiles -> 64x64 (4 waves x 32x32): gemm_out 1024 blocks = 4/CU, gemm_proj 3072.
// Mask bit-pack rewritten coalesced (1 float4/thread + 4 ballots + byte interleave)
// vs 128B-stride/thread (64 cache lines per instruction). attn untouched (R14).

#define BS_    4
#define NSEQ   2048
#define DMODEL 512
#define NH     8
#define DKH    64
#define MROWS  (BS_ * NSEQ)   // 8192
#define NW32   (NSEQ / 32)    // 64 mask words per row
#define NWORDS (BS_ * NSEQ * NSEQ / 32)  // 524288 packed mask words

typedef unsigned short ushort_t;
typedef __attribute__((ext_vector_type(8))) short short8;   // 8 bf16 (4 VGPRs)
typedef __attribute__((ext_vector_type(4))) float floatx4;  // 4 fp32 acc

__device__ __forceinline__ ushort_t f2bf(float f) {
    unsigned int x = __builtin_bit_cast(unsigned int, f);
    unsigned int lsb = (x >> 16) & 1u;
    x += 0x7fffu + lsb;          // round-to-nearest-even
    return (ushort_t)(x >> 16);
}
__device__ __forceinline__ floatx4 mfma_bf16(short8 a, short8 b, floatx4 c) {
    return __builtin_amdgcn_mfma_f32_16x16x32_bf16(a, b, c, 0, 0, 0);
}
__device__ __forceinline__ void gld16(const ushort_t* g, ushort_t* l) {
    __builtin_amdgcn_global_load_lds(
        (const __attribute__((address_space(1))) unsigned int*)g,
        (__attribute__((address_space(3))) unsigned int*)l, 16, 0, 0);
}
__device__ __forceinline__ unsigned int cvt_pk_bf16(float lo, float hi) {
    unsigned int r;
    asm("v_cvt_pk_bf16_f32 %0, %1, %2" : "=v"(r) : "v"(lo), "v"(hi));
    return r;
}
__device__ __forceinline__ float fexp2(float x) {
#if __has_builtin(__builtin_amdgcn_exp2f)
    return __builtin_amdgcn_exp2f(x);   // raw v_exp_f32
#else
    return exp2f(x);
#endif
}
// gfx950: swap a[32:63] <-> b[0:31]
__device__ __forceinline__ void permlane32_swap(unsigned& a, unsigned& b) {
    asm volatile("v_permlane32_swap_b32 %0, %1" : "+v"(a), "+v"(b));
}
// gfx950: swap a[16:31]<->b[0:15] and a[48:63]<->b[32:47]
__device__ __forceinline__ void permlane16_swap(unsigned& a, unsigned& b) {
    asm volatile("v_permlane16_swap_b32 %0, %1" : "+v"(a), "+v"(b));
}
// spread 8 bits of b to positions 0,4,8,...,28
__device__ __forceinline__ unsigned spread4(unsigned b) {
    b = (b | (b << 12)) & 0x000F000Fu;
    b = (b | (b << 6))  & 0x03030303u;
    b = (b | (b << 3))  & 0x11111111u;
    return b;
}

// ---------------- fp32 -> bf16 converts + weights + att_mas bit-pack ----------------
// grid (4096, 8): y=0..2 QKV slices; y=3 weights; y=4..7 mask quarters (coalesced
// float4/thread + 4 ballots; lanes 0..7 of each wave emit the 8 packed words).
__global__ __launch_bounds__(256) void cvt_all(const float* __restrict__ a,
                                               const float* __restrict__ b,
                                               const float* __restrict__ c,
                                               const float* __restrict__ wq,
                                               const float* __restrict__ wk,
                                               const float* __restrict__ wv,
                                               const float* __restrict__ wo,
                                               const float* __restrict__ am,
                                               ushort_t* __restrict__ dst,
                                               ushort_t* __restrict__ wdst,
                                               unsigned int* __restrict__ mb, int n4) {
    const int i = blockIdx.x * blockDim.x + threadIdx.x;
    const int yy = blockIdx.y;
    if (yy >= 4) {
        // g indexes float4s of att_mas; elements 4g..4g+3; word w = elems 32w..32w+31
        const int g = ((yy - 4) * 4096 + blockIdx.x) * 256 + threadIdx.x;
        const float4 v = ((const float4*)am)[g];
        const unsigned long long b0 = __ballot(v.x != 0.f);
        const unsigned long long b1 = __ballot(v.y != 0.f);
        const unsigned long long b2 = __ballot(v.z != 0.f);
        const unsigned long long b3 = __ballot(v.w != 0.f);
        const int l = threadIdx.x & 63;
        if (l < 8) {
            const unsigned B0 = (unsigned)((b0 >> (8 * l)) & 0xFFull);
            const unsigned B1 = (unsigned)((b1 >> (8 * l)) & 0xFFull);
            const unsigned B2 = (unsigned)((b2 >> (8 * l)) & 0xFFull);
            const unsigned B3 = (unsigned)((b3 >> (8 * l)) & 0xFFull);
            const unsigned w = spread4(B0) | (spread4(B1) << 1) |
                               (spread4(B2) << 2) | (spread4(B3) << 3);
            const int g0 = g & ~63;           // wave-base float4 index
            mb[(g0 >> 3) + l] = w;
        }
        return;
    }
    if (yy == 3) {
        const int wn4 = DMODEL * DMODEL / 4;          // 65536 float4 per weight
        if (i < 4 * wn4) {
            const int w = i >> 16;
            const float* src = (w == 0) ? wq : (w == 1) ? wk : (w == 2) ? wv : wo;
            const float4 v = ((const float4*)src)[i & (wn4 - 1)];
            ushort4 o;
            o.x = f2bf(v.x); o.y = f2bf(v.y); o.z = f2bf(v.z); o.w = f2bf(v.w);
            ((ushort4*)wdst)[i] = o;
        }
        return;
    }
    const float* src = (yy == 0) ? a : (yy == 1) ? b : c;
    ushort_t* d = dst + (size_t)yy * ((size_t)n4 * 4);
    const float4 v = ((const float4*)src)[i];
    ushort4 o;
    o.x = f2bf(v.x); o.y = f2bf(v.y); o.z = f2bf(v.z); o.w = f2bf(v.w);
    ((ushort4*)d)[i] = o;
}

// ---------------- fused projection GEMM (Q/K/V via blockIdx.z), 64x64 tile, BK=64 ----------------
// 4 waves x (32x32 out, 2x2 frags). Grid (128, 8, 3) = 3072 blocks -> 8+ blocks/CU.
// Both-sides XOR swizzle: linear gld16 dest, source col16 ^= row&7, read col XOR'd.
__global__ __launch_bounds__(256) void gemm_proj(const ushort_t* __restrict__ Xall,
                                                 const ushort_t* __restrict__ Wall,
                                                 const float* __restrict__ qmas,
                                                 const float* __restrict__ kmas,
                                                 ushort_t* __restrict__ Qh,
                                                 ushort_t* __restrict__ Kh,
                                                 ushort_t* __restrict__ Vt) {
    __shared__ ushort_t As[64 * 64];   // 8 KB
    __shared__ ushort_t Bs[64 * 64];   // 8 KB
    const int z = blockIdx.z;
    const ushort_t* X  = Xall + (size_t)z * MROWS * DMODEL;
    const ushort_t* Wb = Wall + (size_t)z * DMODEL * DMODEL;
    const float* rowmask = (z == 0) ? qmas : kmas;

    const int tid  = threadIdx.x;
    const int wave = tid >> 6;
    const int lane = tid & 63;
    const int l16  = lane & 15;
    const int quad = lane >> 4;
    const int wr   = wave >> 1;
    const int wc   = wave & 1;
    const int m0   = blockIdx.x * 64;
    const int n0   = blockIdx.y * 64;

    floatx4 acc[2][2];
#pragma unroll
    for (int t = 0; t < 2; ++t)
#pragma unroll
        for (int u = 0; u < 2; ++u) acc[t][u] = (floatx4){0.f, 0.f, 0.f, 0.f};

    for (int k0 = 0; k0 < DMODEL; k0 += 64) {
#pragma unroll
        for (int i = 0; i < 2; ++i) {
            const int cch = tid + i * 256;               // 16B chunk id, 0..511
            const int row = cch >> 3;
            const int sc  = 8 * ((cch & 7) ^ (row & 7)); // pre-swizzled source col
            gld16(X  + (size_t)(m0 + row) * DMODEL + k0 + sc, &As[cch * 8]);
            gld16(Wb + (size_t)(n0 + row) * DMODEL + k0 + sc, &Bs[cch * 8]);
        }
        __syncthreads();
#pragma unroll
        for (int kk = 0; kk < 64; kk += 32) {
            const int pc = (((kk >> 3) | quad) ^ (l16 & 7)) * 8;
            short8 a[2], b[2];
#pragma unroll
            for (int t = 0; t < 2; ++t)
                a[t] = *(const short8*)&As[(wr * 32 + t * 16 + l16) * 64 + pc];
#pragma unroll
            for (int u = 0; u < 2; ++u)
                b[u] = *(const short8*)&Bs[(wc * 32 + u * 16 + l16) * 64 + pc];
#pragma unroll
            for (int t = 0; t < 2; ++t)
#pragma unroll
                for (int u = 0; u < 2; ++u) acc[t][u] = mfma_bf16(a[t], b[u], acc[t][u]);
        }
        __syncthreads();
    }

    float rm[2][4];
#pragma unroll
    for (int t = 0; t < 2; ++t)
#pragma unroll
        for (int r = 0; r < 4; ++r)
            rm[t][r] = rowmask[m0 + wr * 32 + t * 16 + quad * 4 + r];
    if (z == 0) {
        // fold log2(e)/sqrt(dk) into Qh so attn uses exp2(S) directly
#pragma unroll
        for (int t = 0; t < 2; ++t)
#pragma unroll
            for (int r = 0; r < 4; ++r) rm[t][r] *= 0.18033688011112042f;
    }

    const int bb    = m0 >> 11;
    const int nbase = (m0 & (NSEQ - 1)) + wr * 32;
#pragma unroll
    for (int t = 0; t < 2; ++t) {
#pragma unroll
        for (int u = 0; u < 2; ++u) {
            const int d = n0 + wc * 32 + u * 16 + l16;
            const int h = d >> 6, cc = d & 63;
            if (z < 2) {
                ushort_t* dst = (z == 0) ? Qh : Kh;
#pragma unroll
                for (int r = 0; r < 4; ++r) {
                    const int n = nbase + t * 16 + quad * 4 + r;
                    dst[((size_t)(bb * NH + h) * NSEQ + n) * DKH + cc] =
                        f2bf(acc[t][u][r] * rm[t][r]);
                }
            } else {
                ushort4 pk;
                pk.x = f2bf(acc[t][u][0] * rm[t][0]);
                pk.y = f2bf(acc[t][u][1] * rm[t][1]);
                pk.z = f2bf(acc[t][u][2] * rm[t][2]);
                pk.w = f2bf(acc[t][u][3] * rm[t][3]);
                const int n = nbase + t * 16 + quad * 4;
                *(ushort4*)(Vt + ((size_t)(bb * NH + h) * DKH + cc) * NSEQ + n) = pk;
            }
        }
    }
}

// ---------------- output GEMM, 64x64 tile, BK=64, swizzled ----------------
// Grid (128, 8) = 1024 blocks = 4 blocks/CU (was 256 = 1/CU: the occupancy hole).
__global__ __launch_bounds__(256) void gemm_out(const ushort_t* __restrict__ X,
                                                const ushort_t* __restrict__ Wb,
                                                const float* __restrict__ rowmask,
                                                float* __restrict__ dst) {
    __shared__ ushort_t As[64 * 64];
    __shared__ ushort_t Bs[64 * 64];
    const int tid  = threadIdx.x;
    const int wave = tid >> 6;
    const int lane = tid & 63;
    const int l16  = lane & 15;
    const int quad = lane >> 4;
    const int wr   = wave >> 1;
    const int wc   = wave & 1;
    const int m0   = blockIdx.x * 64;
    const int n0   = blockIdx.y * 64;

    floatx4 acc[2][2];
#pragma unroll
    for (int t = 0; t < 2; ++t)
#pragma unroll
        for (int u = 0; u < 2; ++u) acc[t][u] = (floatx4){0.f, 0.f, 0.f, 0.f};

    for (int k0 = 0; k0 < DMODEL; k0 += 64) {
#pragma unroll
        for (int i = 0; i < 2; ++i) {
            const int cch = tid + i * 256;
            const int row = cch >> 3;
            const int sc  = 8 * ((cch & 7) ^ (row & 7));
            gld16(X  + (size_t)(m0 + row) * DMODEL + k0 + sc, &As[cch * 8]);
            gld16(Wb + (size_t)(n0 + row) * DMODEL + k0 + sc, &Bs[cch * 8]);
        }
        __syncthreads();
#pragma unroll
        for (int kk = 0; kk < 64; kk += 32) {
            const int pc = (((kk >> 3) | quad) ^ (l16 & 7)) * 8;
            short8 a[2], b[2];
#pragma unroll
            for (int t = 0; t < 2; ++t)
                a[t] = *(const short8*)&As[(wr * 32 + t * 16 + l16) * 64 + pc];
#pragma unroll
            for (int u = 0; u < 2; ++u)
                b[u] = *(const short8*)&Bs[(wc * 32 + u * 16 + l16) * 64 + pc];
#pragma unroll
            for (int t = 0; t < 2; ++t)
#pragma unroll
                for (int u = 0; u < 2; ++u) acc[t][u] = mfma_bf16(a[t], b[u], acc[t][u]);
        }
        __syncthreads();
    }

#pragma unroll
    for (int t = 0; t < 2; ++t) {
#pragma unroll
        for (int r = 0; r < 4; ++r) {
            const int m = m0 + wr * 32 + t * 16 + quad * 4 + r;
            const float rm = rowmask[m];
#pragma unroll
            for (int u = 0; u < 2; ++u) {
                const int d = n0 + wc * 32 + u * 16 + l16;
                dst[(size_t)m * DMODEL + d] = acc[t][u][r] * rm;
            }
        }
    }
}

// ---------------- flash attention: 128-q blocks, 2 q-groups/wave, in-register P ----------------
// (unchanged from R14 — 64.4 us, MfmaUtil ~24%, conflicts 4.19M)
__global__ __launch_bounds__(256) void attn_kernel(const ushort_t* __restrict__ Qh,
                                                   const ushort_t* __restrict__ Kh,
                                                   const ushort_t* __restrict__ Vt,
                                                   const unsigned int* __restrict__ Mb,
                                                   const float* __restrict__ kmas,
                                                   ushort_t* __restrict__ y) {
    __shared__ __align__(16) ushort_t Ks[128 * 72];      // 18432 B
    __shared__ __align__(16) ushort_t Vs[64 * 136];      // 17408 B (total 35840)

    const int tid  = threadIdx.x;
    const int lane = tid & 63;
    const int wave = tid >> 6;
    const int l16  = lane & 15;
    const int quad = lane >> 4;
    const int h    = blockIdx.y;
    const int b    = blockIdx.z;
    const int qw   = blockIdx.x * 128 + wave * 32;   // this wave's 32 q-rows

    const ushort_t* Kb = Kh + (size_t)(b * NH + h) * NSEQ * DKH;
    const ushort_t* Vb = Vt + (size_t)(b * NH + h) * DKH * NSEQ;
    // per-lane mask rows: q = qw + l16 (group 0) and qw + 16 + l16 (group 1)
    const uint4* Mv0 = (const uint4*)(Mb + ((size_t)(b * NSEQ + qw) + l16) * NW32);
    const uint4* Mv1 = (const uint4*)(Mb + ((size_t)(b * NSEQ + qw) + 16 + l16) * NW32);

    const ushort_t* Qp0 = Qh + ((size_t)((b * NH + h) * NSEQ) + qw + l16) * DKH + quad * 8;
    const ushort_t* Qp1 = Qp0 + 16 * DKH;
    const short8 qf0a = *(const short8*)Qp0;
    const short8 qf0b = *(const short8*)(Qp0 + 32);
    const short8 qf1a = *(const short8*)Qp1;
    const short8 qf1b = *(const short8*)(Qp1 + 32);

    // all-ones bf16 B-operand for row-sum MFMA (bf16 1.0 = 0x3F80)
    const short8 ones = {(short)0x3F80, (short)0x3F80, (short)0x3F80, (short)0x3F80,
                         (short)0x3F80, (short)0x3F80, (short)0x3F80, (short)0x3F80};

    floatx4 accA[4], accB[4];
    floatx4 accL0 = (floatx4){0.f, 0.f, 0.f, 0.f};   // row-sums l, group 0
    floatx4 accL1 = (floatx4){0.f, 0.f, 0.f, 0.f};   // row-sums l, group 1
#pragma unroll
    for (int ct = 0; ct < 4; ++ct) {
        accA[ct] = (floatx4){0.f, 0.f, 0.f, 0.f};
        accB[ct] = (floatx4){0.f, 0.f, 0.f, 0.f};
    }

// S fragment FR (compile-time after unroll) -> packed P words for both groups
#define SFRAG(FR, PX0, PY0, PX1, PY1) do {                                         \
    const short8 ka = *(const short8*)&Ks[((FR) * 16 + l16) * 72 + quad * 8];      \
    const short8 kb = *(const short8*)&Ks[((FR) * 16 + l16) * 72 + 32 + quad * 8]; \
    floatx4 s0 = {0.f, 0.f, 0.f, 0.f};                                             \
    s0 = mfma_bf16(ka, qf0a, s0);                                                  \
    s0 = mfma_bf16(kb, qf0b, s0);                                                  \
    floatx4 s1 = {0.f, 0.f, 0.f, 0.f};                                             \
    s1 = mfma_bf16(ka, qf1a, s1);                                                  \
    s1 = mfma_bf16(kb, qf1b, s1);                                                  \
    float p0[4], p1[4];                                                            \
    _Pragma("unroll")                                                              \
    for (int r = 0; r < 4; ++r) {                                                  \
        const int bitp = (((FR) & 1) << 4) + r;                                    \
        const unsigned m0m =                                                       \
            (unsigned)__builtin_amdgcn_sbfe((int)wsh0[(FR) >> 1], bitp, 1);        \
        const unsigned m1m =                                                       \
            (unsigned)__builtin_amdgcn_sbfe((int)wsh1[(FR) >> 1], bitp, 1);        \
        p0[r] = __builtin_bit_cast(float,                                          \
                    __builtin_bit_cast(unsigned, fexp2(s0[r])) & m0m);             \
        p1[r] = __builtin_bit_cast(float,                                          \
                    __builtin_bit_cast(unsigned, fexp2(s1[r])) & m1m);             \
    }                                                                              \
    PX0 = cvt_pk_bf16(p0[0], p0[1]); PY0 = cvt_pk_bf16(p0[2], p0[3]);              \
    PX1 = cvt_pk_bf16(p1[0], p1[1]); PY1 = cvt_pk_bf16(p1[2], p1[3]);              \
} while (0)

    for (int kt = 0; kt < NSEQ / 128; ++kt) {
        const int k0 = kt * 128;

        // ---- gather staging data into VGPRs (coalesced 16B/lane) ----
        short8 kv[4], vv[4];
#pragma unroll
        for (int i = 0; i < 4; ++i) {
            const int c = tid + i * 256;
            kv[i] = *(const short8*)(Kb + (size_t)(k0 + (c >> 3)) * DKH + (c & 7) * 8);
        }
#pragma unroll
        for (int i = 0; i < 4; ++i) {
            const int c = tid + i * 256;
            vv[i] = *(const short8*)(Vb + (size_t)(c >> 4) * NSEQ + k0 + (c & 15) * 8);
        }
        const uint4 mw0 = Mv0[kt];
        const uint4 mw1 = Mv1[kt];

        __syncthreads();   // (a) previous tile's LDS reads complete
#pragma unroll
        for (int i = 0; i < 4; ++i) {
            const int c = tid + i * 256;
            *(short8*)&Ks[(c >> 3) * 72 + (c & 7) * 8] = kv[i];
        }
#pragma unroll
        for (int i = 0; i < 4; ++i) {
            const int c = tid + i * 256;
            *(short8*)&Vs[(c >> 4) * 136 + (c & 15) * 8] = vv[i];
        }
        __syncthreads();   // (b) tile staged

        const unsigned int wsh0[4] = {mw0.x >> (quad * 4), mw0.y >> (quad * 4),
                                      mw0.z >> (quad * 4), mw0.w >> (quad * 4)};
        const unsigned int wsh1[4] = {mw1.x >> (quad * 4), mw1.y >> (quad * 4),
                                      mw1.z >> (quad * 4), mw1.w >> (quad * 4)};

        // ---- fused per-kf: S (2 frags) -> softmax -> permlane transpose -> l + PV ----
#pragma unroll
        for (int kf = 0; kf < 4; ++kf) {
            unsigned xe0, ye0, xo0, yo0;   // group 0: fr even / odd packed words
            unsigned xe1, ye1, xo1, yo1;   // group 1
            SFRAG(kf * 2,     xe0, ye0, xe1, ye1);
            SFRAG(kf * 2 + 1, xo0, yo0, xo1, yo1);

            permlane32_swap(xe0, xo0); permlane32_swap(ye0, yo0);
            permlane16_swap(xe0, xo0); permlane16_swap(ye0, yo0);
            permlane32_swap(xe1, xo1); permlane32_swap(ye1, yo1);
            permlane16_swap(xe1, xo1); permlane16_swap(ye1, yo1);

            const uint4 u0 = {xe0, ye0, xo0, yo0};
            const uint4 u1 = {xe1, ye1, xo1, yo1};
            const short8 pf0 = __builtin_bit_cast(short8, u0);
            const short8 pf1 = __builtin_bit_cast(short8, u1);

            // l += P.1 on the MFMA pipe
            accL0 = mfma_bf16(pf0, ones, accL0);
            accL1 = mfma_bf16(pf1, ones, accL1);

            // O += P.V : each V fragment read once -> both q-groups
#pragma unroll
            for (int ct = 0; ct < 4; ++ct) {
                const short8 vb =
                    *(const short8*)&Vs[(ct * 16 + l16) * 136 + kf * 32 + quad * 8];
                accA[ct] = mfma_bf16(pf0, vb, accA[ct]);
                accB[ct] = mfma_bf16(pf1, vb, accB[ct]);
            }
        }
    }
#undef SFRAG

    // ---- epilogue: l is in accL at exactly (q = qw + quad*4 + r); no shuffles ----
#pragma unroll
    for (int r = 0; r < 4; ++r) {
        const int q0 = qw + quad * 4 + r;
        const int q1 = q0 + 16;
        const float sc0 = kmas[b * NSEQ + q0] / accL0[r];
        const float sc1 = kmas[b * NSEQ + q1] / accL1[r];
#pragma unroll
        for (int ct = 0; ct < 4; ++ct) {
            y[(size_t)(b * NSEQ + q0) * DMODEL + h * DKH + ct * 16 + l16] =
                f2bf(accA[ct][r] * sc0);
            y[(size_t)(b * NSEQ + q1) * DMODEL + h * DKH + ct * 16 + l16] =
                f2bf(accB[ct][r] * sc1);
        }
    }
}

extern "C" void kernel_launch(void* const* d_in, const int* in_sizes, int n_in,
                              void* d_out, int out_size, void* d_ws, size_t ws_size,
                              hipStream_t stream) {
    (void)in_sizes; (void)n_in; (void)out_size; (void)ws_size;
    const float* Q  = (const float*)d_in[0];
    const float* K  = (const float*)d_in[1];
    const float* V  = (const float*)d_in[2];
    const float* qm = (const float*)d_in[3];
    const float* km = (const float*)d_in[4];
    const float* am = (const float*)d_in[5];
    const float* WQ = (const float*)d_in[6];
    const float* WK = (const float*)d_in[7];
    const float* WV = (const float*)d_in[8];
    const float* WO = (const float*)d_in[9];

    const size_t XN = (size_t)MROWS * DMODEL;        // 4,194,304
    const size_t WN = (size_t)DMODEL * DMODEL;       // 262,144
    ushort_t* Xbf = (ushort_t*)d_ws;                 // Q,K,V bf16: 3*XN
    ushort_t* Wbf = Xbf + 3 * XN;                    // WQ,WK,WV,WO bf16: 4*WN
    ushort_t* WOb = Wbf + 3 * WN;
    ushort_t* Qh  = Wbf + 4 * WN;
    ushort_t* Kh  = Qh + XN;
    ushort_t* Vt  = Kh + XN;
    ushort_t* y   = Vt + XN;
    // packed mask lives in d_out (2 MB of 16 MB); gemm_out fully overwrites d_out afterwards
    unsigned int* Mbits = (unsigned int*)d_out;
    float* out = (float*)d_out;

    hipLaunchKernelGGL(cvt_all, dim3(4096, 8), dim3(256), 0, stream,
                       Q, K, V, WQ, WK, WV, WO, am, Xbf, Wbf, Mbits, (int)(XN / 4));

    hipLaunchKernelGGL(gemm_proj, dim3(MROWS / 64, DMODEL / 64, 3), dim3(256), 0, stream,
                       Xbf, Wbf, qm, km, Qh, Kh, Vt);

    hipLaunchKernelGGL(attn_kernel, dim3(NSEQ / 128, NH, BS_), dim3(256), 0, stream,
                       Qh, Kh, Vt, Mbits, km, y);

    hipLaunchKernelGGL(gemm_out, dim3(MROWS / 64, DMODEL / 64), dim3(256), 0, stream,
                       y, WOb, km, out);
}